// Round 8
// baseline (387.355 us; speedup 1.0000x reference)
//
#include <hip/hip_runtime.h>
#include <math.h>

// Problem constants (fixed by setup_inputs)
#define B_  32
#define N_  20000
#define C_  8
#define E_  512
#define H_  8
#define SCALE 0.125f    // 1/sqrt(64)
#define UNSC  9.765625e-4f   // 1/1024 = 1/(32*32) operand pre-scale undo

#define CHUNK 1024
#define NCH   20       // ceil(20000/1024) (top-k chunking)
#define NC3   157      // ceil(20000/128)  (GEMM n-chunks, BN=128)
#define NCG   20       // ceil(NC3/8) nc-groups for XCD swizzle
#define SSZ ((size_t)B_ * H_ * N_)   // per-class S floats (256*20000)

typedef __attribute__((ext_vector_type(8))) _Float16 h8_t;  // 8 fp16 (4 VGPRs)
typedef __attribute__((ext_vector_type(8))) short   s8_t;   // 8 shorts (16 B)
typedef __attribute__((ext_vector_type(4))) float f32x4;    // 16x16 MFMA acc

#define MFMAH(a, b, c) __builtin_amdgcn_mfma_f32_16x16x32_f16(a, b, c, 0, 0, 0)

// async global->LDS, 16B per lane, wave-uniform LDS base + lane*16
#define GLOAD_LDS16(g, l)                                              \
    __builtin_amdgcn_global_load_lds(                                  \
        (const __attribute__((address_space(1))) unsigned int*)(g),    \
        (__attribute__((address_space(3))) unsigned int*)(l), 16, 0, 0)

// RNE round-to-fp16, returns bit pattern + rounded value
__device__ inline unsigned short f16_round(float x, float& fv) {
    _Float16 h = (_Float16)x;
    fv = (float)h;
    union { _Float16 hh; unsigned short us; } u;
    u.hh = h;
    return u.us;
}

#define U2P ((size_t)C_ * 16 * 16 * 512)   // 1,048,576 shorts per plane

// ---------------------------------------------------------------------------
// K_prep (R16): one launch for ALL preprocessing.
// blocks [0, 64): fused q+u2 per (c,h) — recompute the 32x64 q-slice in LDS
//   (exact old k_q2 accumulation order -> bit-identical q), then the old
//   k_u2 body (et-loop internal) reading q from LDS. Placed FIRST so these
//   long blocks start in round 1 and hide under the A-split blocks.
// blocks [64, 64+NC3*16): A-split (2 fp16 planes, R5 swizzle layout).
// ---------------------------------------------------------------------------
__global__ __launch_bounds__(256) void k_prep(
        const float* __restrict__ A, short* __restrict__ A2t,
        const float* __restrict__ x, const float* __restrict__ Wq,
        const float* __restrict__ bq, const float* __restrict__ Wk,
        const float* __restrict__ bk, short* __restrict__ u2,
        float* __restrict__ qb) {
    int bid = blockIdx.x;
    int tid = threadIdx.x;
    if (bid >= 64) {
        // ---- A-split: 2 fp16 planes, (nchunk 128, kstep 32) tiles ----
        int bA = bid - 64;
        int nc = bA >> 4, ks = bA & 15;
        int n = tid >> 1, kg = (tid & 1) * 2;   // logical chunks kg, kg+1 of 4
        int gn = nc * 128 + n;
        const float* ap = A + (size_t)gn * 512 + ks * 32 + kg * 8;
        s8_t vh[2], vm[2];
        #pragma unroll
        for (int g = 0; g < 2; ++g)
            #pragma unroll
            for (int j = 0; j < 8; ++j) {
                float xv = (gn < N_) ? ap[g * 8 + j] * 32.0f : 0.f;
                float fh, fm;
                vh[g][j] = (short)f16_round(xv, fh);
                vm[g][j] = (short)f16_round(xv - fh, fm);
            }
        short* outp = A2t + ((size_t)nc * 16 + ks) * 8192 + n * 32;
        #pragma unroll
        for (int g = 0; g < 2; ++g) {
            int p = ((kg + g) + (n >> 1)) & 3;
            *(s8_t*)(outp + p * 8)        = vh[g];
            *(s8_t*)(outp + 4096 + p * 8) = vm[g];
        }
    } else {
        // ---- fused q+u2 for (c, h) ----
        int h = bid & 7, c = bid >> 3;
        __shared__ float xs[32][66];
        __shared__ float wt[64][66];     // Wq staging, then Wk staging
        __shared__ float qsl[32][66];    // q-slice (b, d)
        int b = tid & 31, grp = tid >> 5;   // grp in 0..7

        // Phase A: q_slice(b,d) = sum_e x(b,e)*Wq[c][h*64+d, e]  (+bq)
        // accumulation order: k0 ascending, kk 0..63 — identical to old k_q2
        float acc8[8] = {};
        const float* Wqc = Wq + (size_t)c * E_ * E_ + (size_t)(h * 64) * E_;
        for (int k0 = 0; k0 < E_; k0 += 64) {
            __syncthreads();
            for (int i = tid; i < 2048; i += 256)
                xs[i >> 6][i & 63] = x[(size_t)(i >> 6) * E_ + k0 + (i & 63)];
            for (int i = tid; i < 4096; i += 256)
                wt[i >> 6][i & 63] = Wqc[(size_t)(i >> 6) * E_ + k0 + (i & 63)];
            __syncthreads();
            #pragma unroll
            for (int kk = 0; kk < 64; ++kk) {
                float xv = xs[b][kk];
                #pragma unroll
                for (int j = 0; j < 8; ++j)
                    acc8[j] += xv * wt[grp * 8 + j][kk];
            }
        }
        __syncthreads();
        #pragma unroll
        for (int j = 0; j < 8; ++j)
            qsl[b][grp * 8 + j] = acc8[j] + bq[c * E_ + h * 64 + grp * 8 + j];
        __syncthreads();

        // Phase B: old k_u2 body, et-loop internal, q from LDS
        int es = grp;
        const float* Wkc = Wk + (size_t)c * E_ * E_ + (size_t)(h * 64) * E_;
        for (int et = 0; et < 8; ++et) {
            int e0 = et * 64;
            __syncthreads();
            for (int i = tid; i < 4096; i += 256)
                wt[i >> 6][i & 63] = Wkc[(size_t)(i >> 6) * E_ + e0 + (i & 63)];
            __syncthreads();
            float acc[8] = {};
            for (int d = 0; d < 64; ++d) {
                float qv = qsl[b][d];
                #pragma unroll
                for (int j = 0; j < 8; ++j)
                    acc[j] += qv * wt[d][es * 8 + j];
            }
            // direct fragment-order store (identical to old k_u2)
            int m   = b * 8 + h;
            int e0s = e0 + es * 8;
            int ks  = e0s >> 5, quad = (e0s & 31) >> 3;
            int lane2 = (m & 15) + 16 * quad;
            int mt  = m >> 4;
            size_t base = ((((size_t)c * 16 + mt) * 16 + ks) * 512)
                          + (size_t)lane2 * 8;
            s8_t vh, vm;
            #pragma unroll
            for (int j = 0; j < 8; ++j) {
                float xv = acc[j] * 32.0f, fh, fm;
                vh[j] = (short)f16_round(xv, fh);
                vm[j] = (short)f16_round(xv - fh, fm);
            }
            *(s8_t*)(u2 + base)       = vh;
            *(s8_t*)(u2 + U2P + base) = vm;
        }
        // qb(c, m) = sum_d q(b,d)*bk — same order as old k_u2
        if (grp == 0) {
            float s = 0.f;
            const float* bkr = bk + c * E_ + h * 64;
            for (int d = 0; d < 64; ++d) s += qsl[b][d] * bkr[d];
            qb[c * 256 + b * 8 + h] = s;
        }
    }
}

// ---------------------------------------------------------------------------
// Main: S(m,n) = member ? exp(SCALE*(dot/1024 + qb)) : 0, 3-product fp16x2
// (hh, hm, mh) via 16x16x32 f16 MFMA.
//
// R16: occupancy notch #3 (the only lever that ever moved this kernel:
// 2->3 waves/SIMD -16%, 3->4 -4%). Wave tile 32x128 -> 32x64:
// acc[2][4] = 32 AGPR -> target 6 waves/SIMD at <=85 regs, LDS 16.9 KB.
// Block = M=128 (mh) x N=64 (nh); grid NCG*2*2*8*CB = 5120.
// A2t swizzle survives the nh split: ((r+64)>>1)&3 == ((r>>1)+32)&3 ==
// (r>>1)&3 mod 4 pattern ✓. DMA: 16 segs x 1024 B ([kh][plane][16-row grp]).
// Zpart gains an nh axis (NC3*2 partials; k_topk loop bound doubles —
// summation regrouping proven tolerated in R15).
// ---------------------------------------------------------------------------
__global__ __launch_bounds__(256, 6) void k_scores_mfma(
        const short* __restrict__ u2, const short* __restrict__ A2t,
        const float* __restrict__ qb, const int* __restrict__ mask,
        float* __restrict__ S, float* __restrict__ Zpart, int c0, int CB) {
    __shared__ __align__(16) short As[8192];   // one 16 KB ks2-tile [kh][pl][64][32]
    __shared__ float sQb[128];
    __shared__ int   sMask[64];
    int bx = blockIdx.x;
    int x     = bx & 7;
    int rest  = bx >> 3;
    int mh    = rest & 1;          // m-half: rows [mh*128, mh*128+128)
    int nh    = (rest >> 1) & 1;   // n-quarter-half: cols [nh*64, nh*64+64)
    int rest2 = rest >> 2;
    int z     = rest2 % CB;
    int g     = rest2 / CB;
    int nc    = g * 8 + x;
    if (nc >= NC3) return;
    int c  = c0 + z;
    int tid = threadIdx.x;
    int lane = tid & 63, w = tid >> 6;
    int quad = lane >> 4, l15 = lane & 15;
    int n0 = nc * 128 + nh * 64;

    if (tid < 128) sQb[tid] = qb[c * 256 + mh * 128 + tid];
    if (tid < 64) {
        int n = n0 + tid;
        sMask[tid] = (n < N_) ? mask[(size_t)n * C_ + c] : 0;
    }

    f32x4 acc[2][4];   // [mt][nt] — wave owns 32 rows x 64 cols
    #pragma unroll
    for (int i = 0; i < 2; ++i)
        #pragma unroll
        for (int j = 0; j < 4; ++j)
            acc[i][j] = (f32x4){0.f, 0.f, 0.f, 0.f};

    const char* tb = (const char*)A2t + (size_t)nc * 262144 + nh * 4096;

    for (int ks2 = 0; ks2 < 8; ++ks2) {
        __syncthreads();   // all waves done reading As (covers sQb/sMask too)
        // async DMA this ks2's 16 KB (2 kh x 2 planes x 64 rows x 64 B):
        // 16 segs of 1024 B, 4 per wave
        const char* src = tb + (size_t)ks2 * 32768;
        #pragma unroll
        for (int t = 0; t < 4; ++t) {
            int seg = w * 4 + t;
            int kh = seg >> 3, pl = (seg >> 2) & 1, rg = seg & 3;
            GLOAD_LDS16(src + kh * 16384 + pl * 8192 + rg * 1024 + lane * 16,
                        (char*)As + seg * 1024);
        }
        __syncthreads();   // compiler drains vmcnt(0) before barrier

        #pragma unroll
        for (int kh = 0; kh < 2; ++kh) {
            int ks = ks2 * 2 + kh;
            const short* Ab = As + kh * 4096;   // [pl 2048][64 rows x 32]
            // A-fragments (u2): 4 global 16B loads, L2/LLC-resident
            h8_t af[2][2];
            #pragma unroll
            for (int mt = 0; mt < 2; ++mt) {
                int mtg = mh * 8 + w * 2 + mt;
                size_t ub = ((((size_t)c * 16 + mtg) * 16 + ks) * 512)
                            + (size_t)lane * 8;
                af[mt][0] = *(const h8_t*)(u2 + ub);
                af[mt][1] = *(const h8_t*)(u2 + U2P + ub);
            }
            // two nt-halves; sched_barrier caps b-frag hoisting (reg budget)
            #pragma unroll
            for (int half = 0; half < 2; ++half) {
                __builtin_amdgcn_sched_barrier(0);
                #pragma unroll
                for (int q2 = 0; q2 < 2; ++q2) {
                    int nt = half * 2 + q2;
                    int r = nt * 16 + l15;
                    const short* bp = Ab + r * 32 + ((quad + (r >> 1)) & 3) * 8;
                    h8_t b0 = *(const h8_t*)bp;
                    h8_t b1 = *(const h8_t*)(bp + 2048);
                    #pragma unroll
                    for (int mt = 0; mt < 2; ++mt) {
                        f32x4 a = acc[mt][nt];
                        a = MFMAH(af[mt][0], b0, a);   // hh
                        a = MFMAH(af[mt][0], b1, a);   // hm
                        a = MFMAH(af[mt][1], b0, a);   // mh
                        acc[mt][nt] = a;
                    }
                }
            }
        }
    }

    // Epilogue: unscale + bias + mask + exp, write S, fused deterministic
    // row-sums.  C/D: col = lane&15, row = quad*4 + r (m89/m91).
    float* Sc = S + (size_t)z * SSZ;
    #pragma unroll
    for (int mt = 0; mt < 2; ++mt) {
        float rs[4] = {0.f, 0.f, 0.f, 0.f};
        #pragma unroll
        for (int nt = 0; nt < 4; ++nt) {
            int nl = nt * 16 + l15;
            int n = n0 + nl;
            int mem = sMask[nl];
            #pragma unroll
            for (int r = 0; r < 4; ++r) {
                int ml = w * 32 + mt * 16 + quad * 4 + r;   // local row in half
                float sc = SCALE * (acc[mt][nt][r] * UNSC + sQb[ml]);
                float ev = mem ? __expf(sc) : 0.f;
                rs[r] += ev;
                if (n < N_) Sc[(size_t)(mh * 128 + ml) * N_ + n] = ev;
            }
        }
        #pragma unroll
        for (int r = 0; r < 4; ++r) {
            float v = rs[r];
            v += __shfl_xor(v, 1); v += __shfl_xor(v, 2);
            v += __shfl_xor(v, 4); v += __shfl_xor(v, 8);
            if (l15 == 0) {
                int ml = w * 32 + mt * 16 + quad * 4 + r;
                Zpart[((size_t)(nc * 2 + nh) * C_ + c) * 256 + mh * 128 + ml] = v;
            }
        }
    }
}

// ---------------------------------------------------------------------------
// K3: fully fused [Z-sum + head-average + chunk top-ns + final merge].
// grid (B, CB), block 640 = 10 waves; wave w owns chunks {2w, 2w+1}.
// Z: parallel across all 64 lanes (lane = slice*8 + h over NC3*2 partials,
// xor-shfl tree). Per chunk: 16 values/lane, ns rounds of {local scan ->
// 64-lane butterfly -> removal} (tie-break: value desc, index asc). Winners
// -> LDS; wave 0 merges 100 candidates (exact old-topk2 semantics).
// ---------------------------------------------------------------------------
__global__ __launch_bounds__(640) void k_topk(
        const float* __restrict__ S, const float* __restrict__ Zpart,
        float* __restrict__ out, int c0, int ns) {
    int b = blockIdx.x, z = blockIdx.y;
    int c = c0 + z;
    int tid = threadIdx.x;
    int lane = tid & 63, w = tid >> 6;   // w in 0..9
    const float* Sc = S + (size_t)z * SSZ;

    __shared__ float2 wcand[NCH * 8];    // [chunk*ns + j], ns <= 8

    // ---- Z (all 64 lanes): h = lane&7, slice = lane>>3 over nc2 ----
    float zrl;
    {
        int h = lane & 7, sl = lane >> 3;
        const float* zp = Zpart + (size_t)c * 256 + b * 8 + h;
        float s = 0.f;
        for (int nc2 = sl; nc2 < NC3 * 2; nc2 += 8)
            s += zp[(size_t)nc2 * (C_ * 256)];
        s += __shfl_xor(s, 8, 64);
        s += __shfl_xor(s, 16, 64);
        s += __shfl_xor(s, 32, 64);
        zrl = 0.125f / s;
    }
    float zr[H_];
    #pragma unroll
    for (int h = 0; h < H_; ++h) zr[h] = __shfl(zrl, h, 64);

    // ---- per-wave: 2 chunks sequentially ----
    for (int p = 0; p < 2; ++p) {
        int chunk = w * 2 + p;
        int base = chunk * CHUNK + lane * 4;   // slot s=j*4+t -> n=base+j*256+t
        float va[16];
        #pragma unroll
        for (int s = 0; s < 16; ++s) va[s] = 0.f;
        bool ok[4];
        #pragma unroll
        for (int j = 0; j < 4; ++j) ok[j] = (base + j * 256) < N_;  // N_%4==0

        #pragma unroll
        for (int h = 0; h < H_; ++h) {
            const float* row = Sc + (size_t)(b * H_ + h) * N_;
            float wz = zr[h];
            #pragma unroll
            for (int j = 0; j < 4; ++j) {
                if (ok[j]) {
                    const float4 sv = *(const float4*)&row[base + j * 256];
                    va[j * 4 + 0] += sv.x * wz;
                    va[j * 4 + 1] += sv.y * wz;
                    va[j * 4 + 2] += sv.z * wz;
                    va[j * 4 + 3] += sv.w * wz;
                }
            }
        }
        #pragma unroll
        for (int j = 0; j < 4; ++j)
            if (!ok[j]) {
                va[j * 4 + 0] = -1.f; va[j * 4 + 1] = -1.f;
                va[j * 4 + 2] = -1.f; va[j * 4 + 3] = -1.f;
            }

        for (int j = 0; j < ns; ++j) {
            // local max over 16 slots; ascending scan + strict > = lowest n
            float bv = va[0]; int bs = 0;
            #pragma unroll
            for (int s = 1; s < 16; ++s)
                if (va[s] > bv) { bv = va[s]; bs = s; }
            int bn = ok[bs >> 2] ? (base + ((bs >> 2) << 8) + (bs & 3)) : N_;
            // 64-lane butterfly (all lanes converge on wave winner)
            #pragma unroll
            for (int off = 1; off < 64; off <<= 1) {
                float ov = __shfl_xor(bv, off, 64);
                int   on = __shfl_xor(bn, off, 64);
                if (ov > bv || (ov == bv && on < bn)) { bv = ov; bn = on; }
            }
            if (lane == 0) wcand[chunk * ns + j] = make_float2(bv, (float)bn);
            // in-register removal: only the owner lane matches bn
            #pragma unroll
            for (int s = 0; s < 16; ++s) {
                int n_s = base + ((s >> 2) << 8) + (s & 3);
                if (n_s == bn) va[s] = -2.f;
            }
        }
    }
    __syncthreads();

    // ---- wave 0: merge 100 candidates (exact old-topk2 semantics) ----
    if (w == 0) {
        int ncand = NCH * ns;   // 100
        float v0 = -3.f, v1 = -3.f;
        int   i0 = N_ + 1, i1 = N_ + 2;
        if (lane < ncand)      { float2 e = wcand[lane];      v0 = e.x; i0 = (int)e.y; }
        if (lane + 64 < ncand) { float2 e = wcand[lane + 64]; v1 = e.x; i1 = (int)e.y; }
        for (int j = 0; j < ns; ++j) {
            float bv = v0; int bn = i0;
            if (v1 > bv || (v1 == bv && i1 < bn)) { bv = v1; bn = i1; }
            #pragma unroll
            for (int off = 1; off < 64; off <<= 1) {
                float ov = __shfl_xor(bv, off, 64);
                int   on = __shfl_xor(bn, off, 64);
                if (ov > bv || (ov == bv && on < bn)) { bv = ov; bn = on; }
            }
            if (lane == 0) {
                out[((size_t)b * C_ + c) * ns + j] = (float)bn;
                out[(size_t)B_ * C_ * ns + ((size_t)b * C_ + c) * ns + j] = bv;
            }
            if (i0 == bn) v0 = -3.f;
            if (i1 == bn) v1 = -3.f;
        }
    }
}

// ---------------------------------------------------------------------------
extern "C" void kernel_launch(void* const* d_in, const int* in_sizes, int n_in,
                              void* d_out, int out_size, void* d_ws, size_t ws_size,
                              hipStream_t stream) {
    const float* x    = (const float*)d_in[0];  // (B,E)
    const float* A    = (const float*)d_in[1];  // (N,E)
    const int*   mask = (const int*)  d_in[2];  // (N,C)
    const float* Wq   = (const float*)d_in[3];  // (C,E,E)
    const float* bq   = (const float*)d_in[4];  // (C,E)
    const float* Wk   = (const float*)d_in[5];  // (C,E,E)
    const float* bk   = (const float*)d_in[6];  // (C,E)
    float* out = (float*)d_out;

    int ns = out_size / (2 * B_ * C_);          // = n_samples (5)

    // Workspace carve (floats) — q, u, Z, cand buffers all removed
    float* ws = (float*)d_ws;
    float* qb    = ws;                                    // 2048
    float* Zpart = qb + (size_t)C_ * B_ * H_;             // NC3*2*8*256 = 643072
    short* u2    = (short*)(Zpart + (size_t)NC3 * 2 * C_ * 256); // 2*1048576 shorts
    short* A2t   = u2 + 2 * U2P;                               // NC3*16*8192 shorts
    float* S     = (float*)(A2t + (size_t)NC3 * 16 * 8192);
    size_t fixedFloats = (size_t)(S - ws);

    int CB = 8;
    while (CB > 1 && (fixedFloats + (size_t)CB * SSZ + 16) * 4 > ws_size)
        CB >>= 1;

    k_prep<<<64 + NC3 * 16, 256, 0, stream>>>(A, A2t, x, Wq, bq, Wk, bk, u2, qb);

    for (int c0 = 0; c0 < C_; c0 += CB) {
        // grid: (g, z, nh, mh, x) packed; 4 sub-blocks per (nc, c)
        k_scores_mfma<<<NCG * 4 * 8 * CB, 256, 0, stream>>>(u2, A2t, qb, mask, S, Zpart, c0, CB);
        k_topk<<<dim3(B_, CB), 640, 0, stream>>>(S, Zpart, out, c0, ns);
    }
}

// Round 9
// 341.321 us; speedup vs baseline: 1.1349x; 1.1349x over previous
//
#include <hip/hip_runtime.h>
#include <math.h>

// Problem constants (fixed by setup_inputs)
#define B_  32
#define N_  20000
#define C_  8
#define E_  512
#define H_  8
#define SCALE 0.125f    // 1/sqrt(64)
#define UNSC  9.765625e-4f   // 1/1024 = 1/(32*32) operand pre-scale undo

#define CHUNK 1024
#define NCH   20       // ceil(20000/1024) (top-k chunking)
#define NC3   157      // ceil(20000/128)  (GEMM n-chunks, BN=128)
#define NCG   20       // ceil(NC3/8) nc-groups for XCD swizzle
#define SSZ ((size_t)B_ * H_ * N_)   // per-class S floats (256*20000)

typedef __attribute__((ext_vector_type(8))) _Float16 h8_t;  // 8 fp16 (4 VGPRs)
typedef __attribute__((ext_vector_type(8))) short   s8_t;   // 8 shorts (16 B)
typedef __attribute__((ext_vector_type(4))) float f32x4;    // 16x16 MFMA acc

#define MFMAH(a, b, c) __builtin_amdgcn_mfma_f32_16x16x32_f16(a, b, c, 0, 0, 0)

// async global->LDS, 16B per lane, wave-uniform LDS base + lane*16
#define GLOAD_LDS16(g, l)                                              \
    __builtin_amdgcn_global_load_lds(                                  \
        (const __attribute__((address_space(1))) unsigned int*)(g),    \
        (__attribute__((address_space(3))) unsigned int*)(l), 16, 0, 0)

// RNE round-to-fp16, returns bit pattern + rounded value
__device__ inline unsigned short f16_round(float x, float& fv) {
    _Float16 h = (_Float16)x;
    fv = (float)h;
    union { _Float16 hh; unsigned short us; } u;
    u.hh = h;
    return u.us;
}

#define U2P ((size_t)C_ * 16 * 16 * 512)   // 1,048,576 shorts per plane

// ---------------------------------------------------------------------------
// K_prep (R17 = R15 revert): fused [k_split_A2 || k_q2] only.
// R16's q+u2 fusion collapsed TLP (64 fat blocks, Occ 7.6%, 134 us) — the
// W-heavy u2 work needs its 512-block grid back.
// blocks [0, NC3*16): A-split (nc = bid>>4, ks = bid&15), R5 swizzle layout.
// blocks [NC3*16, NC3*16+512): q2 (ft = r&63, c = r>>6).
// ---------------------------------------------------------------------------
__global__ __launch_bounds__(256) void k_prep(
        const float* __restrict__ A, short* __restrict__ A2t,
        const float* __restrict__ x, const float* __restrict__ Wq,
        const float* __restrict__ bq, float* __restrict__ q) {
    int bid = blockIdx.x;
    int tid = threadIdx.x;
    if (bid < NC3 * 16) {
        // ---- A-split: 2 fp16 planes, (nchunk 128, kstep 32) tiles ----
        int nc = bid >> 4, ks = bid & 15;
        int n = tid >> 1, kg = (tid & 1) * 2;   // logical chunks kg, kg+1 of 4
        int gn = nc * 128 + n;
        const float* ap = A + (size_t)gn * 512 + ks * 32 + kg * 8;
        s8_t vh[2], vm[2];
        #pragma unroll
        for (int g = 0; g < 2; ++g)
            #pragma unroll
            for (int j = 0; j < 8; ++j) {
                float xv = (gn < N_) ? ap[g * 8 + j] * 32.0f : 0.f;
                float fh, fm;
                vh[g][j] = (short)f16_round(xv, fh);
                vm[g][j] = (short)f16_round(xv - fh, fm);
            }
        short* outp = A2t + ((size_t)nc * 16 + ks) * 8192 + n * 32;
        #pragma unroll
        for (int g = 0; g < 2; ++g) {
            int p = ((kg + g) + (n >> 1)) & 3;
            *(s8_t*)(outp + p * 8)        = vh[g];
            *(s8_t*)(outp + 4096 + p * 8) = vm[g];
        }
    } else {
        // ---- q2: q(c,b,f) = sum_e x(b,e) * Wq[c][f,e] + bq[c][f] ----
        int r = bid - NC3 * 16;
        int ft = r & 63, c = r >> 6;
        int f0 = ft * 8;
        __shared__ float wsm[8][66];
        __shared__ float xs[32][66];
        int b = tid & 31, fs = tid >> 5;
        float acc = 0.f;
        const float* W = Wq + (size_t)c * E_ * E_;
        for (int k0 = 0; k0 < E_; k0 += 64) {
            __syncthreads();
            for (int i = tid; i < 512; i += 256)
                wsm[i >> 6][i & 63] = W[(size_t)(f0 + (i >> 6)) * E_ + k0 + (i & 63)];
            for (int i = tid; i < 2048; i += 256)
                xs[i >> 6][i & 63] = x[(size_t)(i >> 6) * E_ + k0 + (i & 63)];
            __syncthreads();
            #pragma unroll
            for (int kk = 0; kk < 64; ++kk)
                acc += xs[b][kk] * wsm[fs][kk];
        }
        q[((size_t)c * B_ + b) * E_ + f0 + fs] = acc + bq[c * E_ + f0 + fs];
    }
}

// ---------------------------------------------------------------------------
// K1b (R15 version, reverted): u(c, m=(b*8+h), e) = sum_d q(c,b,h*64+d) *
// Wk[c][h*64+d, e], written DIRECTLY as 2 fp16 planes in 16x16x32 A-fragment
// order. 512 blocks — the TLP the R16 fusion destroyed.
// ---------------------------------------------------------------------------
__global__ __launch_bounds__(256) void k_u2(
        const float* __restrict__ q, const float* __restrict__ Wk,
        const float* __restrict__ bk, short* __restrict__ u2,
        float* __restrict__ qb) {
    int et = blockIdx.x, h = blockIdx.y, c = blockIdx.z;
    int e0 = et * 64;
    __shared__ float qs[32][66];
    __shared__ float wk[64][66];
    int tid = threadIdx.x;
    int b = tid & 31, es = tid >> 5;
    for (int i = tid; i < 2048; i += 256)
        qs[i >> 6][i & 63] = q[((size_t)c * B_ + (i >> 6)) * E_ + h * 64 + (i & 63)];
    const float* W = Wk + (size_t)c * E_ * E_ + (size_t)(h * 64) * E_;
    for (int i = tid; i < 4096; i += 256)
        wk[i >> 6][i & 63] = W[(size_t)(i >> 6) * E_ + e0 + (i & 63)];
    __syncthreads();
    float acc[8] = {};
    for (int d = 0; d < 64; ++d) {
        float qv = qs[b][d];
        #pragma unroll
        for (int j = 0; j < 8; ++j)
            acc[j] += qv * wk[d][es * 8 + j];
    }
    // direct fragment-order store (old k_split_u2 math, u round-trip removed)
    int m   = b * 8 + h;
    int e0s = e0 + es * 8;
    int ks  = e0s >> 5, quad = (e0s & 31) >> 3;
    int lane = (m & 15) + 16 * quad;
    int mt  = m >> 4;
    size_t base = ((((size_t)c * 16 + mt) * 16 + ks) * 512) + (size_t)lane * 8;
    s8_t vh, vm;
    #pragma unroll
    for (int j = 0; j < 8; ++j) {
        float xv = acc[j] * 32.0f, fh, fm;
        vh[j] = (short)f16_round(xv, fh);
        vm[j] = (short)f16_round(xv - fh, fm);
    }
    *(s8_t*)(u2 + base)       = vh;
    *(s8_t*)(u2 + U2P + base) = vm;
    if (et == 0 && es == 0) {
        float s = 0.f;
        const float* bkr = bk + c * E_ + h * 64;
        for (int d = 0; d < 64; ++d) s += qs[b][d] * bkr[d];
        qb[c * 256 + b * 8 + h] = s;
    }
}

// ---------------------------------------------------------------------------
// Main: S(m,n) = member ? exp(SCALE*(dot/1024 + qb)) : 0, 3-product fp16x2
// (hh, hm, mh) via 16x16x32 f16 MFMA.
//
// R16 32x64 wave tile KEPT (inferred ~118 -> ~81 us from R16's total
// decomposition; this round's counters verify directly): acc[2][4] = 32
// AGPR -> 6 waves/SIMD at __launch_bounds__(256,6), LDS 16.9 KB.
// Block = M=128 (mh) x N=64 (nh); grid NCG*4*8*CB.
// ---------------------------------------------------------------------------
__global__ __launch_bounds__(256, 6) void k_scores_mfma(
        const short* __restrict__ u2, const short* __restrict__ A2t,
        const float* __restrict__ qb, const int* __restrict__ mask,
        float* __restrict__ S, float* __restrict__ Zpart, int c0, int CB) {
    __shared__ __align__(16) short As[8192];   // one 16 KB ks2-tile [kh][pl][64][32]
    __shared__ float sQb[128];
    __shared__ int   sMask[64];
    int bx = blockIdx.x;
    int x     = bx & 7;
    int rest  = bx >> 3;
    int mh    = rest & 1;          // m-half: rows [mh*128, mh*128+128)
    int nh    = (rest >> 1) & 1;   // n-half: cols [nh*64, nh*64+64)
    int rest2 = rest >> 2;
    int z     = rest2 % CB;
    int g     = rest2 / CB;
    int nc    = g * 8 + x;
    if (nc >= NC3) return;
    int c  = c0 + z;
    int tid = threadIdx.x;
    int lane = tid & 63, w = tid >> 6;
    int quad = lane >> 4, l15 = lane & 15;
    int n0 = nc * 128 + nh * 64;

    if (tid < 128) sQb[tid] = qb[c * 256 + mh * 128 + tid];
    if (tid < 64) {
        int n = n0 + tid;
        sMask[tid] = (n < N_) ? mask[(size_t)n * C_ + c] : 0;
    }

    f32x4 acc[2][4];   // [mt][nt] — wave owns 32 rows x 64 cols
    #pragma unroll
    for (int i = 0; i < 2; ++i)
        #pragma unroll
        for (int j = 0; j < 4; ++j)
            acc[i][j] = (f32x4){0.f, 0.f, 0.f, 0.f};

    const char* tb = (const char*)A2t + (size_t)nc * 262144 + nh * 4096;

    for (int ks2 = 0; ks2 < 8; ++ks2) {
        __syncthreads();   // all waves done reading As (covers sQb/sMask too)
        // async DMA this ks2's 16 KB (2 kh x 2 planes x 64 rows x 64 B):
        // 16 segs of 1024 B, 4 per wave
        const char* src = tb + (size_t)ks2 * 32768;
        #pragma unroll
        for (int t = 0; t < 4; ++t) {
            int seg = w * 4 + t;
            int kh = seg >> 3, pl = (seg >> 2) & 1, rg = seg & 3;
            GLOAD_LDS16(src + kh * 16384 + pl * 8192 + rg * 1024 + lane * 16,
                        (char*)As + seg * 1024);
        }
        __syncthreads();   // compiler drains vmcnt(0) before barrier

        #pragma unroll
        for (int kh = 0; kh < 2; ++kh) {
            int ks = ks2 * 2 + kh;
            const short* Ab = As + kh * 4096;   // [pl 2048][64 rows x 32]
            // A-fragments (u2): 4 global 16B loads, L2/LLC-resident
            h8_t af[2][2];
            #pragma unroll
            for (int mt = 0; mt < 2; ++mt) {
                int mtg = mh * 8 + w * 2 + mt;
                size_t ub = ((((size_t)c * 16 + mtg) * 16 + ks) * 512)
                            + (size_t)lane * 8;
                af[mt][0] = *(const h8_t*)(u2 + ub);
                af[mt][1] = *(const h8_t*)(u2 + U2P + ub);
            }
            // two nt-halves; sched_barrier caps b-frag hoisting (reg budget)
            #pragma unroll
            for (int half = 0; half < 2; ++half) {
                __builtin_amdgcn_sched_barrier(0);
                #pragma unroll
                for (int q2 = 0; q2 < 2; ++q2) {
                    int nt = half * 2 + q2;
                    int r = nt * 16 + l15;
                    const short* bp = Ab + r * 32 + ((quad + (r >> 1)) & 3) * 8;
                    h8_t b0 = *(const h8_t*)bp;
                    h8_t b1 = *(const h8_t*)(bp + 2048);
                    #pragma unroll
                    for (int mt = 0; mt < 2; ++mt) {
                        f32x4 a = acc[mt][nt];
                        a = MFMAH(af[mt][0], b0, a);   // hh
                        a = MFMAH(af[mt][0], b1, a);   // hm
                        a = MFMAH(af[mt][1], b0, a);   // mh
                        acc[mt][nt] = a;
                    }
                }
            }
        }
    }

    // Epilogue: unscale + bias + mask + exp, write S, fused deterministic
    // row-sums.  C/D: col = lane&15, row = quad*4 + r (m89/m91).
    float* Sc = S + (size_t)z * SSZ;
    #pragma unroll
    for (int mt = 0; mt < 2; ++mt) {
        float rs[4] = {0.f, 0.f, 0.f, 0.f};
        #pragma unroll
        for (int nt = 0; nt < 4; ++nt) {
            int nl = nt * 16 + l15;
            int n = n0 + nl;
            int mem = sMask[nl];
            #pragma unroll
            for (int r = 0; r < 4; ++r) {
                int ml = w * 32 + mt * 16 + quad * 4 + r;   // local row in half
                float sc = SCALE * (acc[mt][nt][r] * UNSC + sQb[ml]);
                float ev = mem ? __expf(sc) : 0.f;
                rs[r] += ev;
                if (n < N_) Sc[(size_t)(mh * 128 + ml) * N_ + n] = ev;
            }
        }
        #pragma unroll
        for (int r = 0; r < 4; ++r) {
            float v = rs[r];
            v += __shfl_xor(v, 1); v += __shfl_xor(v, 2);
            v += __shfl_xor(v, 4); v += __shfl_xor(v, 8);
            if (l15 == 0) {
                int ml = w * 32 + mt * 16 + quad * 4 + r;
                Zpart[((size_t)(nc * 2 + nh) * C_ + c) * 256 + mh * 128 + ml] = v;
            }
        }
    }
}

// ---------------------------------------------------------------------------
// K3: fully fused [Z-sum + head-average + chunk top-ns + final merge].
// grid (B, CB), block 640 = 10 waves; wave w owns chunks {2w, 2w+1}.
// Z: parallel across all 64 lanes (lane = slice*8 + h over NC3*2 partials,
// xor-shfl tree). Per chunk: 16 values/lane, ns rounds of {local scan ->
// 64-lane butterfly -> removal} (tie-break: value desc, index asc). Winners
// -> LDS; wave 0 merges 100 candidates (exact old-topk2 semantics).
// ---------------------------------------------------------------------------
__global__ __launch_bounds__(640) void k_topk(
        const float* __restrict__ S, const float* __restrict__ Zpart,
        float* __restrict__ out, int c0, int ns) {
    int b = blockIdx.x, z = blockIdx.y;
    int c = c0 + z;
    int tid = threadIdx.x;
    int lane = tid & 63, w = tid >> 6;   // w in 0..9
    const float* Sc = S + (size_t)z * SSZ;

    __shared__ float2 wcand[NCH * 8];    // [chunk*ns + j], ns <= 8

    // ---- Z (all 64 lanes): h = lane&7, slice = lane>>3 over nc2 ----
    float zrl;
    {
        int h = lane & 7, sl = lane >> 3;
        const float* zp = Zpart + (size_t)c * 256 + b * 8 + h;
        float s = 0.f;
        for (int nc2 = sl; nc2 < NC3 * 2; nc2 += 8)
            s += zp[(size_t)nc2 * (C_ * 256)];
        s += __shfl_xor(s, 8, 64);
        s += __shfl_xor(s, 16, 64);
        s += __shfl_xor(s, 32, 64);
        zrl = 0.125f / s;
    }
    float zr[H_];
    #pragma unroll
    for (int h = 0; h < H_; ++h) zr[h] = __shfl(zrl, h, 64);

    // ---- per-wave: 2 chunks sequentially ----
    for (int p = 0; p < 2; ++p) {
        int chunk = w * 2 + p;
        int base = chunk * CHUNK + lane * 4;   // slot s=j*4+t -> n=base+j*256+t
        float va[16];
        #pragma unroll
        for (int s = 0; s < 16; ++s) va[s] = 0.f;
        bool ok[4];
        #pragma unroll
        for (int j = 0; j < 4; ++j) ok[j] = (base + j * 256) < N_;  // N_%4==0

        #pragma unroll
        for (int h = 0; h < H_; ++h) {
            const float* row = Sc + (size_t)(b * H_ + h) * N_;
            float wz = zr[h];
            #pragma unroll
            for (int j = 0; j < 4; ++j) {
                if (ok[j]) {
                    const float4 sv = *(const float4*)&row[base + j * 256];
                    va[j * 4 + 0] += sv.x * wz;
                    va[j * 4 + 1] += sv.y * wz;
                    va[j * 4 + 2] += sv.z * wz;
                    va[j * 4 + 3] += sv.w * wz;
                }
            }
        }
        #pragma unroll
        for (int j = 0; j < 4; ++j)
            if (!ok[j]) {
                va[j * 4 + 0] = -1.f; va[j * 4 + 1] = -1.f;
                va[j * 4 + 2] = -1.f; va[j * 4 + 3] = -1.f;
            }

        for (int j = 0; j < ns; ++j) {
            // local max over 16 slots; ascending scan + strict > = lowest n
            float bv = va[0]; int bs = 0;
            #pragma unroll
            for (int s = 1; s < 16; ++s)
                if (va[s] > bv) { bv = va[s]; bs = s; }
            int bn = ok[bs >> 2] ? (base + ((bs >> 2) << 8) + (bs & 3)) : N_;
            // 64-lane butterfly (all lanes converge on wave winner)
            #pragma unroll
            for (int off = 1; off < 64; off <<= 1) {
                float ov = __shfl_xor(bv, off, 64);
                int   on = __shfl_xor(bn, off, 64);
                if (ov > bv || (ov == bv && on < bn)) { bv = ov; bn = on; }
            }
            if (lane == 0) wcand[chunk * ns + j] = make_float2(bv, (float)bn);
            // in-register removal: only the owner lane matches bn
            #pragma unroll
            for (int s = 0; s < 16; ++s) {
                int n_s = base + ((s >> 2) << 8) + (s & 3);
                if (n_s == bn) va[s] = -2.f;
            }
        }
    }
    __syncthreads();

    // ---- wave 0: merge 100 candidates (exact old-topk2 semantics) ----
    if (w == 0) {
        int ncand = NCH * ns;   // 100
        float v0 = -3.f, v1 = -3.f;
        int   i0 = N_ + 1, i1 = N_ + 2;
        if (lane < ncand)      { float2 e = wcand[lane];      v0 = e.x; i0 = (int)e.y; }
        if (lane + 64 < ncand) { float2 e = wcand[lane + 64]; v1 = e.x; i1 = (int)e.y; }
        for (int j = 0; j < ns; ++j) {
            float bv = v0; int bn = i0;
            if (v1 > bv || (v1 == bv && i1 < bn)) { bv = v1; bn = i1; }
            #pragma unroll
            for (int off = 1; off < 64; off <<= 1) {
                float ov = __shfl_xor(bv, off, 64);
                int   on = __shfl_xor(bn, off, 64);
                if (ov > bv || (ov == bv && on < bn)) { bv = ov; bn = on; }
            }
            if (lane == 0) {
                out[((size_t)b * C_ + c) * ns + j] = (float)bn;
                out[(size_t)B_ * C_ * ns + ((size_t)b * C_ + c) * ns + j] = bv;
            }
            if (i0 == bn) v0 = -3.f;
            if (i1 == bn) v1 = -3.f;
        }
    }
}

// ---------------------------------------------------------------------------
extern "C" void kernel_launch(void* const* d_in, const int* in_sizes, int n_in,
                              void* d_out, int out_size, void* d_ws, size_t ws_size,
                              hipStream_t stream) {
    const float* x    = (const float*)d_in[0];  // (B,E)
    const float* A    = (const float*)d_in[1];  // (N,E)
    const int*   mask = (const int*)  d_in[2];  // (N,C)
    const float* Wq   = (const float*)d_in[3];  // (C,E,E)
    const float* bq   = (const float*)d_in[4];  // (C,E)
    const float* Wk   = (const float*)d_in[5];  // (C,E,E)
    const float* bk   = (const float*)d_in[6];  // (C,E)
    float* out = (float*)d_out;

    int ns = out_size / (2 * B_ * C_);          // = n_samples (5)

    // Workspace carve (floats)
    float* ws = (float*)d_ws;
    float* q     = ws;                                    // 131072
    float* qb    = q  + (size_t)C_ * B_ * E_;             // 2048
    float* Zpart = qb + (size_t)C_ * B_ * H_;             // NC3*2*8*256 = 643072
    short* u2    = (short*)(Zpart + (size_t)NC3 * 2 * C_ * 256); // 2*1048576 shorts
    short* A2t   = u2 + 2 * U2P;                               // NC3*16*8192 shorts
    float* S     = (float*)(A2t + (size_t)NC3 * 16 * 8192);
    size_t fixedFloats = (size_t)(S - ws);

    int CB = 8;
    while (CB > 1 && (fixedFloats + (size_t)CB * SSZ + 16) * 4 > ws_size)
        CB >>= 1;

    k_prep<<<NC3 * 16 + 512, 256, 0, stream>>>(A, A2t, x, Wq, bq, q);
    k_u2<<<dim3(8, H_, C_), 256, 0, stream>>>(q, Wk, bk, u2, qb);

    for (int c0 = 0; c0 < C_; c0 += CB) {
        // grid: (g, z, nh, mh, x) packed; 4 sub-blocks per (nc, c)
        k_scores_mfma<<<NCG * 4 * 8 * CB, 256, 0, stream>>>(u2, A2t, qb, mask, S, Zpart, c0, CB);
        k_topk<<<dim3(B_, CB), 640, 0, stream>>>(S, Zpart, out, c0, ns);
    }
}

// Round 10
// 328.725 us; speedup vs baseline: 1.1784x; 1.0383x over previous
//
#include <hip/hip_runtime.h>
#include <math.h>

// Problem constants (fixed by setup_inputs)
#define B_  32
#define N_  20000
#define C_  8
#define E_  512
#define H_  8
#define SCALE 0.125f    // 1/sqrt(64)
#define UNSC  9.765625e-4f   // 1/1024 = 1/(32*32) operand pre-scale undo

#define CHUNK 1024
#define NCH   20       // ceil(20000/1024) (top-k chunking)
#define NC3   157      // ceil(20000/128)  (GEMM n-chunks, BN=128)
#define NCG   20       // ceil(NC3/8) nc-groups for XCD swizzle
#define SSZ ((size_t)B_ * H_ * N_)   // per-class S floats (256*20000)

typedef __attribute__((ext_vector_type(8))) _Float16 h8_t;  // 8 fp16 (4 VGPRs)
typedef __attribute__((ext_vector_type(8))) short   s8_t;   // 8 shorts (16 B)
typedef __attribute__((ext_vector_type(4))) float f32x4;    // 16x16 MFMA acc

#define MFMAH(a, b, c) __builtin_amdgcn_mfma_f32_16x16x32_f16(a, b, c, 0, 0, 0)

// async global->LDS, 16B per lane, wave-uniform LDS base + lane*16
#define GLOAD_LDS16(g, l)                                              \
    __builtin_amdgcn_global_load_lds(                                  \
        (const __attribute__((address_space(1))) unsigned int*)(g),    \
        (__attribute__((address_space(3))) unsigned int*)(l), 16, 0, 0)

// RNE round-to-fp16, returns bit pattern + rounded value
__device__ inline unsigned short f16_round(float x, float& fv) {
    _Float16 h = (_Float16)x;
    fv = (float)h;
    union { _Float16 hh; unsigned short us; } u;
    u.hh = h;
    return u.us;
}

#define U2P ((size_t)C_ * 16 * 16 * 512)   // 1,048,576 shorts per plane

// ---------------------------------------------------------------------------
// K_prep: fused [k_split_A2 || k_q2] — independent works, one launch.
// blocks [0, NC3*16): A-split (nc = bid>>4, ks = bid&15), R5 swizzle layout.
// blocks [NC3*16, NC3*16+512): q2 (ft = r&63, c = r>>6).
// ---------------------------------------------------------------------------
__global__ __launch_bounds__(256) void k_prep(
        const float* __restrict__ A, short* __restrict__ A2t,
        const float* __restrict__ x, const float* __restrict__ Wq,
        const float* __restrict__ bq, float* __restrict__ q) {
    int bid = blockIdx.x;
    int tid = threadIdx.x;
    if (bid < NC3 * 16) {
        // ---- A-split: 2 fp16 planes, (nchunk 128, kstep 32) tiles ----
        int nc = bid >> 4, ks = bid & 15;
        int n = tid >> 1, kg = (tid & 1) * 2;   // logical chunks kg, kg+1 of 4
        int gn = nc * 128 + n;
        const float* ap = A + (size_t)gn * 512 + ks * 32 + kg * 8;
        s8_t vh[2], vm[2];
        #pragma unroll
        for (int g = 0; g < 2; ++g)
            #pragma unroll
            for (int j = 0; j < 8; ++j) {
                float xv = (gn < N_) ? ap[g * 8 + j] * 32.0f : 0.f;
                float fh, fm;
                vh[g][j] = (short)f16_round(xv, fh);
                vm[g][j] = (short)f16_round(xv - fh, fm);
            }
        short* outp = A2t + ((size_t)nc * 16 + ks) * 8192 + n * 32;
        #pragma unroll
        for (int g = 0; g < 2; ++g) {
            int p = ((kg + g) + (n >> 1)) & 3;
            *(s8_t*)(outp + p * 8)        = vh[g];
            *(s8_t*)(outp + 4096 + p * 8) = vm[g];
        }
    } else {
        // ---- q2: q(c,b,f) = sum_e x(b,e) * Wq[c][f,e] + bq[c][f] ----
        int r = bid - NC3 * 16;
        int ft = r & 63, c = r >> 6;
        int f0 = ft * 8;
        __shared__ float wsm[8][66];
        __shared__ float xs[32][66];
        int b = tid & 31, fs = tid >> 5;
        float acc = 0.f;
        const float* W = Wq + (size_t)c * E_ * E_;
        for (int k0 = 0; k0 < E_; k0 += 64) {
            __syncthreads();
            for (int i = tid; i < 512; i += 256)
                wsm[i >> 6][i & 63] = W[(size_t)(f0 + (i >> 6)) * E_ + k0 + (i & 63)];
            for (int i = tid; i < 2048; i += 256)
                xs[i >> 6][i & 63] = x[(size_t)(i >> 6) * E_ + k0 + (i & 63)];
            __syncthreads();
            #pragma unroll
            for (int kk = 0; kk < 64; ++kk)
                acc += xs[b][kk] * wsm[fs][kk];
        }
        q[((size_t)c * B_ + b) * E_ + f0 + fs] = acc + bq[c * E_ + f0 + fs];
    }
}

// ---------------------------------------------------------------------------
// K1b: u(c, m=(b*8+h), e) = sum_d q(c,b,h*64+d) * Wk[c][h*64+d, e], written
// DIRECTLY as 2 fp16 planes in 16x16x32 A-fragment order. 512 blocks.
// ---------------------------------------------------------------------------
__global__ __launch_bounds__(256) void k_u2(
        const float* __restrict__ q, const float* __restrict__ Wk,
        const float* __restrict__ bk, short* __restrict__ u2,
        float* __restrict__ qb) {
    int et = blockIdx.x, h = blockIdx.y, c = blockIdx.z;
    int e0 = et * 64;
    __shared__ float qs[32][66];
    __shared__ float wk[64][66];
    int tid = threadIdx.x;
    int b = tid & 31, es = tid >> 5;
    for (int i = tid; i < 2048; i += 256)
        qs[i >> 6][i & 63] = q[((size_t)c * B_ + (i >> 6)) * E_ + h * 64 + (i & 63)];
    const float* W = Wk + (size_t)c * E_ * E_ + (size_t)(h * 64) * E_;
    for (int i = tid; i < 4096; i += 256)
        wk[i >> 6][i & 63] = W[(size_t)(i >> 6) * E_ + e0 + (i & 63)];
    __syncthreads();
    float acc[8] = {};
    for (int d = 0; d < 64; ++d) {
        float qv = qs[b][d];
        #pragma unroll
        for (int j = 0; j < 8; ++j)
            acc[j] += qv * wk[d][es * 8 + j];
    }
    int m   = b * 8 + h;
    int e0s = e0 + es * 8;
    int ks  = e0s >> 5, quad = (e0s & 31) >> 3;
    int lane = (m & 15) + 16 * quad;
    int mt  = m >> 4;
    size_t base = ((((size_t)c * 16 + mt) * 16 + ks) * 512) + (size_t)lane * 8;
    s8_t vh, vm;
    #pragma unroll
    for (int j = 0; j < 8; ++j) {
        float xv = acc[j] * 32.0f, fh, fm;
        vh[j] = (short)f16_round(xv, fh);
        vm[j] = (short)f16_round(xv - fh, fm);
    }
    *(s8_t*)(u2 + base)       = vh;
    *(s8_t*)(u2 + U2P + base) = vm;
    if (et == 0 && es == 0) {
        float s = 0.f;
        const float* bkr = bk + c * E_ + h * 64;
        for (int d = 0; d < 64; ++d) s += qs[b][d] * bkr[d];
        qb[c * 256 + b * 8 + h] = s;
    }
}

// ---------------------------------------------------------------------------
// Main: S(m,n) = member ? exp(SCALE*(dot/1024 + qb)) : 0, 3-product fp16x2
// (hh, hm, mh) via 16x16x32 f16 MFMA.
//
// R18: EXACT revert to the R15 optimum (118.6 us, MfmaUtil 49, Occ 36).
// Occupancy ladder measured: 2 waves/SIMD 147us, 3 waves 123, 4 waves 118.6,
// 6 waves (32x64 tile) 128.5 — (256,4) + 32x128 wave tile is the local
// optimum; both neighbors verified worse. Schedule experiments (R9/R10)
// were nulls. This kernel is done.
// ---------------------------------------------------------------------------
__global__ __launch_bounds__(256, 4) void k_scores_mfma(
        const short* __restrict__ u2, const short* __restrict__ A2t,
        const float* __restrict__ qb, const int* __restrict__ mask,
        float* __restrict__ S, float* __restrict__ Zpart, int c0, int CB) {
    __shared__ __align__(16) short As[16384];   // one 32 KB ks2-tile (2 kh)
    __shared__ float sQb[128];
    __shared__ int   sMask[128];
    int bx = blockIdx.x;
    int x     = bx & 7;
    int rest  = bx >> 3;
    int mh    = rest & 1;          // m-half: rows [mh*128, mh*128+128)
    int rest2 = rest >> 1;
    int z     = rest2 % CB;
    int g     = rest2 / CB;
    int nc    = g * 8 + x;
    if (nc >= NC3) return;
    int c  = c0 + z;
    int tid = threadIdx.x;
    int lane = tid & 63, w = tid >> 6;
    int quad = lane >> 4, l15 = lane & 15;
    int n0 = nc * 128;

    if (tid < 128) {
        sQb[tid] = qb[c * 256 + mh * 128 + tid];
        int n = n0 + tid;
        sMask[tid] = (n < N_) ? mask[(size_t)n * C_ + c] : 0;
    }

    f32x4 acc[2][8];   // [mt][nt] — wave owns 32 rows x 128 cols
    #pragma unroll
    for (int i = 0; i < 2; ++i)
        #pragma unroll
        for (int j = 0; j < 8; ++j)
            acc[i][j] = (f32x4){0.f, 0.f, 0.f, 0.f};

    const char* tb = (const char*)A2t + (size_t)nc * 262144;

    for (int ks2 = 0; ks2 < 8; ++ks2) {
        __syncthreads();   // all waves done reading As (and covers sQb/sMask)
        // async DMA this ks2's 32 KB (two 16 KB kh tiles): 32 segs of 1024 B
        const char* src = tb + (size_t)ks2 * 32768;
        #pragma unroll
        for (int t = 0; t < 8; ++t) {
            int seg = w * 8 + t;
            GLOAD_LDS16(src + (size_t)seg * 1024 + lane * 16,
                        (char*)As + seg * 1024);
        }
        __syncthreads();   // compiler drains vmcnt(0) before barrier

        #pragma unroll
        for (int kh = 0; kh < 2; ++kh) {
            int ks = ks2 * 2 + kh;
            const short* Ab = As + kh * 8192;
            // A-fragments (u2): 4 global 16B loads, L2/LLC-resident
            h8_t af[2][2];
            #pragma unroll
            for (int mt = 0; mt < 2; ++mt) {
                int mtg = mh * 8 + w * 2 + mt;
                size_t ub = ((((size_t)c * 16 + mtg) * 16 + ks) * 512)
                            + (size_t)lane * 8;
                af[mt][0] = *(const h8_t*)(u2 + ub);
                af[mt][1] = *(const h8_t*)(u2 + U2P + ub);
            }
            // two nt-halves; sched_barrier caps b-frag hoisting (reg budget)
            #pragma unroll
            for (int half = 0; half < 2; ++half) {
                __builtin_amdgcn_sched_barrier(0);
                #pragma unroll
                for (int q4 = 0; q4 < 4; ++q4) {
                    int nt = half * 4 + q4;
                    int r = nt * 16 + l15;
                    const short* bp = Ab + r * 32 + ((quad + (r >> 1)) & 3) * 8;
                    h8_t b0 = *(const h8_t*)bp;
                    h8_t b1 = *(const h8_t*)(bp + 4096);
                    #pragma unroll
                    for (int mt = 0; mt < 2; ++mt) {
                        f32x4 a = acc[mt][nt];
                        a = MFMAH(af[mt][0], b0, a);   // hh
                        a = MFMAH(af[mt][0], b1, a);   // hm
                        a = MFMAH(af[mt][1], b0, a);   // mh
                        acc[mt][nt] = a;
                    }
                }
            }
        }
    }

    // Epilogue: unscale + bias + mask + exp, write S, fused deterministic
    // row-sums.  C/D: col = lane&15, row = quad*4 + r (m89/m91).
    float* Sc = S + (size_t)z * SSZ;
    #pragma unroll
    for (int mt = 0; mt < 2; ++mt) {
        float rs[4] = {0.f, 0.f, 0.f, 0.f};
        #pragma unroll
        for (int nt = 0; nt < 8; ++nt) {
            int nl = nt * 16 + l15;
            int n = n0 + nl;
            int mem = sMask[nl];
            #pragma unroll
            for (int r = 0; r < 4; ++r) {
                int ml = w * 32 + mt * 16 + quad * 4 + r;   // local row in half
                float sc = SCALE * (acc[mt][nt][r] * UNSC + sQb[ml]);
                float ev = mem ? __expf(sc) : 0.f;
                rs[r] += ev;
                if (n < N_) Sc[(size_t)(mh * 128 + ml) * N_ + n] = ev;
            }
        }
        #pragma unroll
        for (int r = 0; r < 4; ++r) {
            float v = rs[r];
            v += __shfl_xor(v, 1); v += __shfl_xor(v, 2);
            v += __shfl_xor(v, 4); v += __shfl_xor(v, 8);
            if (l15 == 0) {
                int ml = w * 32 + mt * 16 + quad * 4 + r;
                Zpart[((size_t)nc * C_ + c) * 256 + mh * 128 + ml] = v;
            }
        }
    }
}

// ---------------------------------------------------------------------------
// K3: fully fused [Z-sum + head-average + chunk top-ns + final merge].
// grid (B, CB), block 640 = 10 waves; wave w owns chunks {2w, 2w+1}.
// R18: the two chunks' LOAD phases are merged (va[2][16], all indices
// compile-time -> registers): both chunks' 4 float4 loads issue per h
// iteration, doubling memory-level parallelism in the 164 MB S-read phase.
// Selection rounds stay per-chunk (chunk-local top-ns semantics unchanged;
// tie-break: value desc, index asc). Winners -> LDS; wave 0 merges 100
// candidates (exact old-topk2 semantics).
// ---------------------------------------------------------------------------
__global__ __launch_bounds__(640) void k_topk(
        const float* __restrict__ S, const float* __restrict__ Zpart,
        float* __restrict__ out, int c0, int ns) {
    int b = blockIdx.x, z = blockIdx.y;
    int c = c0 + z;
    int tid = threadIdx.x;
    int lane = tid & 63, w = tid >> 6;   // w in 0..9
    const float* Sc = S + (size_t)z * SSZ;

    __shared__ float2 wcand[NCH * 8];    // [chunk*ns + j], ns <= 8

    // ---- Z (all 64 lanes): h = lane&7, slice = lane>>3 over nc ----
    float zrl;
    {
        int h = lane & 7, sl = lane >> 3;
        const float* zp = Zpart + (size_t)c * 256 + b * 8 + h;
        float s = 0.f;
        for (int nc = sl; nc < NC3; nc += 8)
            s += zp[(size_t)nc * (C_ * 256)];
        s += __shfl_xor(s, 8, 64);
        s += __shfl_xor(s, 16, 64);
        s += __shfl_xor(s, 32, 64);
        zrl = 0.125f / s;
    }
    float zr[H_];
    #pragma unroll
    for (int h = 0; h < H_; ++h) zr[h] = __shfl(zrl, h, 64);

    // ---- merged load phase: both chunks of this wave ----
    int base0 = (w * 2) * CHUNK + lane * 4;       // chunk 2w
    int base1 = (w * 2 + 1) * CHUNK + lane * 4;   // chunk 2w+1
    float va[2][16];
    #pragma unroll
    for (int p = 0; p < 2; ++p)
        #pragma unroll
        for (int s = 0; s < 16; ++s) va[p][s] = 0.f;
    bool ok[2][4];
    #pragma unroll
    for (int j = 0; j < 4; ++j) {
        ok[0][j] = (base0 + j * 256) < N_;   // N_%4==0
        ok[1][j] = (base1 + j * 256) < N_;
    }

    #pragma unroll
    for (int h = 0; h < H_; ++h) {
        const float* row = Sc + (size_t)(b * H_ + h) * N_;
        float wz = zr[h];
        #pragma unroll
        for (int j = 0; j < 4; ++j) {
            if (ok[0][j]) {
                const float4 sv = *(const float4*)&row[base0 + j * 256];
                va[0][j * 4 + 0] += sv.x * wz; va[0][j * 4 + 1] += sv.y * wz;
                va[0][j * 4 + 2] += sv.z * wz; va[0][j * 4 + 3] += sv.w * wz;
            }
            if (ok[1][j]) {
                const float4 sv = *(const float4*)&row[base1 + j * 256];
                va[1][j * 4 + 0] += sv.x * wz; va[1][j * 4 + 1] += sv.y * wz;
                va[1][j * 4 + 2] += sv.z * wz; va[1][j * 4 + 3] += sv.w * wz;
            }
        }
    }
    #pragma unroll
    for (int p = 0; p < 2; ++p)
        #pragma unroll
        for (int j = 0; j < 4; ++j)
            if (!ok[p][j]) {
                va[p][j * 4 + 0] = -1.f; va[p][j * 4 + 1] = -1.f;
                va[p][j * 4 + 2] = -1.f; va[p][j * 4 + 3] = -1.f;
            }

    // ---- selection rounds, per chunk (semantics identical to R15) ----
    #pragma unroll
    for (int p = 0; p < 2; ++p) {
        int chunk = w * 2 + p;
        int base = p ? base1 : base0;
        float2* cp0 = wcand + chunk * ns;
        for (int j = 0; j < ns; ++j) {
            float bv = va[p][0]; int bs = 0;
            #pragma unroll
            for (int s = 1; s < 16; ++s)
                if (va[p][s] > bv) { bv = va[p][s]; bs = s; }
            int bn = ok[p][bs >> 2] ? (base + ((bs >> 2) << 8) + (bs & 3)) : N_;
            #pragma unroll
            for (int off = 1; off < 64; off <<= 1) {
                float ov = __shfl_xor(bv, off, 64);
                int   on = __shfl_xor(bn, off, 64);
                if (ov > bv || (ov == bv && on < bn)) { bv = ov; bn = on; }
            }
            if (lane == 0) cp0[j] = make_float2(bv, (float)bn);
            #pragma unroll
            for (int s = 0; s < 16; ++s) {
                int n_s = base + ((s >> 2) << 8) + (s & 3);
                if (n_s == bn) va[p][s] = -2.f;
            }
        }
    }
    __syncthreads();

    // ---- wave 0: merge 100 candidates (exact old-topk2 semantics) ----
    if (w == 0) {
        int ncand = NCH * ns;   // 100
        float v0 = -3.f, v1 = -3.f;
        int   i0 = N_ + 1, i1 = N_ + 2;
        if (lane < ncand)      { float2 e = wcand[lane];      v0 = e.x; i0 = (int)e.y; }
        if (lane + 64 < ncand) { float2 e = wcand[lane + 64]; v1 = e.x; i1 = (int)e.y; }
        for (int j = 0; j < ns; ++j) {
            float bv = v0; int bn = i0;
            if (v1 > bv || (v1 == bv && i1 < bn)) { bv = v1; bn = i1; }
            #pragma unroll
            for (int off = 1; off < 64; off <<= 1) {
                float ov = __shfl_xor(bv, off, 64);
                int   on = __shfl_xor(bn, off, 64);
                if (ov > bv || (ov == bv && on < bn)) { bv = ov; bn = on; }
            }
            if (lane == 0) {
                out[((size_t)b * C_ + c) * ns + j] = (float)bn;
                out[(size_t)B_ * C_ * ns + ((size_t)b * C_ + c) * ns + j] = bv;
            }
            if (i0 == bn) v0 = -3.f;
            if (i1 == bn) v1 = -3.f;
        }
    }
}

// ---------------------------------------------------------------------------
extern "C" void kernel_launch(void* const* d_in, const int* in_sizes, int n_in,
                              void* d_out, int out_size, void* d_ws, size_t ws_size,
                              hipStream_t stream) {
    const float* x    = (const float*)d_in[0];  // (B,E)
    const float* A    = (const float*)d_in[1];  // (N,E)
    const int*   mask = (const int*)  d_in[2];  // (N,C)
    const float* Wq   = (const float*)d_in[3];  // (C,E,E)
    const float* bq   = (const float*)d_in[4];  // (C,E)
    const float* Wk   = (const float*)d_in[5];  // (C,E,E)
    const float* bk   = (const float*)d_in[6];  // (C,E)
    float* out = (float*)d_out;

    int ns = out_size / (2 * B_ * C_);          // = n_samples (5)

    // Workspace carve (floats)
    float* ws = (float*)d_ws;
    float* q     = ws;                                    // 131072
    float* qb    = q  + (size_t)C_ * B_ * E_;             // 2048
    float* Zpart = qb + (size_t)C_ * B_ * H_;             // NC3*8*256 = 321536
    short* u2    = (short*)(Zpart + (size_t)NC3 * C_ * 256);   // 2*1048576 shorts
    short* A2t   = u2 + 2 * U2P;                               // NC3*16*8192 shorts
    float* S     = (float*)(A2t + (size_t)NC3 * 16 * 8192);
    size_t fixedFloats = (size_t)(S - ws);

    int CB = 8;
    while (CB > 1 && (fixedFloats + (size_t)CB * SSZ + 16) * 4 > ws_size)
        CB >>= 1;

    k_prep<<<NC3 * 16 + 512, 256, 0, stream>>>(A, A2t, x, Wq, bq, q);
    k_u2<<<dim3(8, H_, C_), 256, 0, stream>>>(q, Wk, bk, u2, qb);

    for (int c0 = 0; c0 < C_; c0 += CB) {
        // grid: (g, z, mh, x) packed; 2 m-half blocks per (nc, c)
        k_scores_mfma<<<NCG * 2 * 8 * CB, 256, 0, stream>>>(u2, A2t, qb, mask, S, Zpart, c0, CB);
        k_topk<<<dim3(B_, CB), 640, 0, stream>>>(S, Zpart, out, c0, ns);
    }
}

// Round 12
// 319.166 us; speedup vs baseline: 1.2136x; 1.0299x over previous
//
#include <hip/hip_runtime.h>
#include <math.h>

// Problem constants (fixed by setup_inputs)
#define B_  32
#define N_  20000
#define C_  8
#define E_  512
#define H_  8
#define SCALE 0.125f    // 1/sqrt(64)
#define UNSC  9.765625e-4f   // 1/1024 = 1/(32*32) operand pre-scale undo

#define CHUNK 1024
#define NCH   20       // ceil(20000/1024) (top-k chunking)
#define NC3   157      // ceil(20000/128)  (GEMM n-chunks, BN=128)
#define NCG   20       // ceil(NC3/8) nc-groups for XCD swizzle
#define SSZ ((size_t)B_ * H_ * N_)   // per-class S floats (256*20000)

typedef __attribute__((ext_vector_type(8))) _Float16 h8_t;  // 8 fp16 (4 VGPRs)
typedef __attribute__((ext_vector_type(8))) short   s8_t;   // 8 shorts (16 B)
typedef __attribute__((ext_vector_type(4))) float f32x4;    // 16x16 MFMA acc

#define MFMAH(a, b, c) __builtin_amdgcn_mfma_f32_16x16x32_f16(a, b, c, 0, 0, 0)

// async global->LDS, 16B per lane, wave-uniform LDS base + lane*16
#define GLOAD_LDS16(g, l)                                              \
    __builtin_amdgcn_global_load_lds(                                  \
        (const __attribute__((address_space(1))) unsigned int*)(g),    \
        (__attribute__((address_space(3))) unsigned int*)(l), 16, 0, 0)

// RNE round-to-fp16, returns bit pattern + rounded value
__device__ inline unsigned short f16_round(float x, float& fv) {
    _Float16 h = (_Float16)x;
    fv = (float)h;
    union { _Float16 hh; unsigned short us; } u;
    u.hh = h;
    return u.us;
}

#define U2P ((size_t)C_ * 16 * 16 * 512)   // 1,048,576 shorts per plane

// ---------------------------------------------------------------------------
// K_prep: fused [k_split_A2 || k_q2] — independent works, one launch.
// blocks [0, NC3*16): A-split (nc = bid>>4, ks = bid&15), R5 swizzle layout.
// blocks [NC3*16, NC3*16+512): q2 (ft = r&63, c = r>>6).
// ---------------------------------------------------------------------------
__global__ __launch_bounds__(256) void k_prep(
        const float* __restrict__ A, short* __restrict__ A2t,
        const float* __restrict__ x, const float* __restrict__ Wq,
        const float* __restrict__ bq, float* __restrict__ q) {
    int bid = blockIdx.x;
    int tid = threadIdx.x;
    if (bid < NC3 * 16) {
        // ---- A-split: 2 fp16 planes, (nchunk 128, kstep 32) tiles ----
        int nc = bid >> 4, ks = bid & 15;
        int n = tid >> 1, kg = (tid & 1) * 2;   // logical chunks kg, kg+1 of 4
        int gn = nc * 128 + n;
        const float* ap = A + (size_t)gn * 512 + ks * 32 + kg * 8;
        s8_t vh[2], vm[2];
        #pragma unroll
        for (int g = 0; g < 2; ++g)
            #pragma unroll
            for (int j = 0; j < 8; ++j) {
                float xv = (gn < N_) ? ap[g * 8 + j] * 32.0f : 0.f;
                float fh, fm;
                vh[g][j] = (short)f16_round(xv, fh);
                vm[g][j] = (short)f16_round(xv - fh, fm);
            }
        short* outp = A2t + ((size_t)nc * 16 + ks) * 8192 + n * 32;
        #pragma unroll
        for (int g = 0; g < 2; ++g) {
            int p = ((kg + g) + (n >> 1)) & 3;
            *(s8_t*)(outp + p * 8)        = vh[g];
            *(s8_t*)(outp + 4096 + p * 8) = vm[g];
        }
    } else {
        // ---- q2: q(c,b,f) = sum_e x(b,e) * Wq[c][f,e] + bq[c][f] ----
        int r = bid - NC3 * 16;
        int ft = r & 63, c = r >> 6;
        int f0 = ft * 8;
        __shared__ float wsm[8][66];
        __shared__ float xs[32][66];
        int b = tid & 31, fs = tid >> 5;
        float acc = 0.f;
        const float* W = Wq + (size_t)c * E_ * E_;
        for (int k0 = 0; k0 < E_; k0 += 64) {
            __syncthreads();
            for (int i = tid; i < 512; i += 256)
                wsm[i >> 6][i & 63] = W[(size_t)(f0 + (i >> 6)) * E_ + k0 + (i & 63)];
            for (int i = tid; i < 2048; i += 256)
                xs[i >> 6][i & 63] = x[(size_t)(i >> 6) * E_ + k0 + (i & 63)];
            __syncthreads();
            #pragma unroll
            for (int kk = 0; kk < 64; ++kk)
                acc += xs[b][kk] * wsm[fs][kk];
        }
        q[((size_t)c * B_ + b) * E_ + f0 + fs] = acc + bq[c * E_ + f0 + fs];
    }
}

// ---------------------------------------------------------------------------
// K1b: u(c, m=(b*8+h), e) = sum_d q(c,b,h*64+d) * Wk[c][h*64+d, e], written
// DIRECTLY as 2 fp16 planes in 16x16x32 A-fragment order. 512 blocks.
// ---------------------------------------------------------------------------
__global__ __launch_bounds__(256) void k_u2(
        const float* __restrict__ q, const float* __restrict__ Wk,
        const float* __restrict__ bk, short* __restrict__ u2,
        float* __restrict__ qb) {
    int et = blockIdx.x, h = blockIdx.y, c = blockIdx.z;
    int e0 = et * 64;
    __shared__ float qs[32][66];
    __shared__ float wk[64][66];
    int tid = threadIdx.x;
    int b = tid & 31, es = tid >> 5;
    for (int i = tid; i < 2048; i += 256)
        qs[i >> 6][i & 63] = q[((size_t)c * B_ + (i >> 6)) * E_ + h * 64 + (i & 63)];
    const float* W = Wk + (size_t)c * E_ * E_ + (size_t)(h * 64) * E_;
    for (int i = tid; i < 4096; i += 256)
        wk[i >> 6][i & 63] = W[(size_t)(i >> 6) * E_ + e0 + (i & 63)];
    __syncthreads();
    float acc[8] = {};
    for (int d = 0; d < 64; ++d) {
        float qv = qs[b][d];
        #pragma unroll
        for (int j = 0; j < 8; ++j)
            acc[j] += qv * wk[d][es * 8 + j];
    }
    int m   = b * 8 + h;
    int e0s = e0 + es * 8;
    int ks  = e0s >> 5, quad = (e0s & 31) >> 3;
    int lane = (m & 15) + 16 * quad;
    int mt  = m >> 4;
    size_t base = ((((size_t)c * 16 + mt) * 16 + ks) * 512) + (size_t)lane * 8;
    s8_t vh, vm;
    #pragma unroll
    for (int j = 0; j < 8; ++j) {
        float xv = acc[j] * 32.0f, fh, fm;
        vh[j] = (short)f16_round(xv, fh);
        vm[j] = (short)f16_round(xv - fh, fm);
    }
    *(s8_t*)(u2 + base)       = vh;
    *(s8_t*)(u2 + U2P + base) = vm;
    if (et == 0 && es == 0) {
        float s = 0.f;
        const float* bkr = bk + c * E_ + h * 64;
        for (int d = 0; d < 64; ++d) s += qs[b][d] * bkr[d];
        qb[c * 256 + b * 8 + h] = s;
    }
}

// ---------------------------------------------------------------------------
// Main: S(m,n) = member ? exp(SCALE*(dot/1024 + qb)) : 0, 3-product fp16x2
// (hh, hm, mh) via 16x16x32 f16 MFMA.
// Verified local optimum: (256,4), 32x128 wave tile, f32 S.
// - occupancy ladder: 2w 147us / 3w 123 / 4w 118.6 / 6w(32x64) 128.5
// - schedule experiments (dbuf, 4-phase+setprio): both perfect nulls
// - fp16 S: index flips (R19) — top-k boundary gaps ~2% mean, 1280
//   boundaries -> fp16's 5e-4 rounding flips tens of them. f32 S required.
// ---------------------------------------------------------------------------
__global__ __launch_bounds__(256, 4) void k_scores_mfma(
        const short* __restrict__ u2, const short* __restrict__ A2t,
        const float* __restrict__ qb, const int* __restrict__ mask,
        float* __restrict__ S, float* __restrict__ Zpart, int c0, int CB) {
    __shared__ __align__(16) short As[16384];   // one 32 KB ks2-tile (2 kh)
    __shared__ float sQb[128];
    __shared__ int   sMask[128];
    int bx = blockIdx.x;
    int x     = bx & 7;
    int rest  = bx >> 3;
    int mh    = rest & 1;          // m-half: rows [mh*128, mh*128+128)
    int rest2 = rest >> 1;
    int z     = rest2 % CB;
    int g     = rest2 / CB;
    int nc    = g * 8 + x;
    if (nc >= NC3) return;
    int c  = c0 + z;
    int tid = threadIdx.x;
    int lane = tid & 63, w = tid >> 6;
    int quad = lane >> 4, l15 = lane & 15;
    int n0 = nc * 128;

    if (tid < 128) {
        sQb[tid] = qb[c * 256 + mh * 128 + tid];
        int n = n0 + tid;
        sMask[tid] = (n < N_) ? mask[(size_t)n * C_ + c] : 0;
    }

    f32x4 acc[2][8];   // [mt][nt] — wave owns 32 rows x 128 cols
    #pragma unroll
    for (int i = 0; i < 2; ++i)
        #pragma unroll
        for (int j = 0; j < 8; ++j)
            acc[i][j] = (f32x4){0.f, 0.f, 0.f, 0.f};

    const char* tb = (const char*)A2t + (size_t)nc * 262144;

    for (int ks2 = 0; ks2 < 8; ++ks2) {
        __syncthreads();   // all waves done reading As (and covers sQb/sMask)
        // async DMA this ks2's 32 KB (two 16 KB kh tiles): 32 segs of 1024 B
        const char* src = tb + (size_t)ks2 * 32768;
        #pragma unroll
        for (int t = 0; t < 8; ++t) {
            int seg = w * 8 + t;
            GLOAD_LDS16(src + (size_t)seg * 1024 + lane * 16,
                        (char*)As + seg * 1024);
        }
        __syncthreads();   // compiler drains vmcnt(0) before barrier

        #pragma unroll
        for (int kh = 0; kh < 2; ++kh) {
            int ks = ks2 * 2 + kh;
            const short* Ab = As + kh * 8192;
            // A-fragments (u2): 4 global 16B loads, L2/LLC-resident
            h8_t af[2][2];
            #pragma unroll
            for (int mt = 0; mt < 2; ++mt) {
                int mtg = mh * 8 + w * 2 + mt;
                size_t ub = ((((size_t)c * 16 + mtg) * 16 + ks) * 512)
                            + (size_t)lane * 8;
                af[mt][0] = *(const h8_t*)(u2 + ub);
                af[mt][1] = *(const h8_t*)(u2 + U2P + ub);
            }
            // two nt-halves; sched_barrier caps b-frag hoisting (reg budget)
            #pragma unroll
            for (int half = 0; half < 2; ++half) {
                __builtin_amdgcn_sched_barrier(0);
                #pragma unroll
                for (int q4 = 0; q4 < 4; ++q4) {
                    int nt = half * 4 + q4;
                    int r = nt * 16 + l15;
                    const short* bp = Ab + r * 32 + ((quad + (r >> 1)) & 3) * 8;
                    h8_t b0 = *(const h8_t*)bp;
                    h8_t b1 = *(const h8_t*)(bp + 4096);
                    #pragma unroll
                    for (int mt = 0; mt < 2; ++mt) {
                        f32x4 a = acc[mt][nt];
                        a = MFMAH(af[mt][0], b0, a);   // hh
                        a = MFMAH(af[mt][0], b1, a);   // hm
                        a = MFMAH(af[mt][1], b0, a);   // mh
                        acc[mt][nt] = a;
                    }
                }
            }
        }
    }

    // Epilogue: unscale + bias + mask + exp, write S, fused deterministic
    // row-sums.  C/D: col = lane&15, row = quad*4 + r (m89/m91).
    float* Sc = S + (size_t)z * SSZ;
    #pragma unroll
    for (int mt = 0; mt < 2; ++mt) {
        float rs[4] = {0.f, 0.f, 0.f, 0.f};
        #pragma unroll
        for (int nt = 0; nt < 8; ++nt) {
            int nl = nt * 16 + l15;
            int n = n0 + nl;
            int mem = sMask[nl];
            #pragma unroll
            for (int r = 0; r < 4; ++r) {
                int ml = w * 32 + mt * 16 + quad * 4 + r;   // local row in half
                float sc = SCALE * (acc[mt][nt][r] * UNSC + sQb[ml]);
                float ev = mem ? __expf(sc) : 0.f;
                rs[r] += ev;
                if (n < N_) Sc[(size_t)(mh * 128 + ml) * N_ + n] = ev;
            }
        }
        #pragma unroll
        for (int r = 0; r < 4; ++r) {
            float v = rs[r];
            v += __shfl_xor(v, 1); v += __shfl_xor(v, 2);
            v += __shfl_xor(v, 4); v += __shfl_xor(v, 8);
            if (l15 == 0) {
                int ml = w * 32 + mt * 16 + quad * 4 + r;
                Zpart[((size_t)nc * C_ + c) * 256 + mh * 128 + ml] = v;
            }
        }
    }
}

// ---------------------------------------------------------------------------
// K3: fully fused [Z-sum + head-average + chunk top-ns + final merge].
// grid (B, CB), block 640 = 10 waves; wave w owns chunks {2w, 2w+1}.
// Z: parallel across all 64 lanes (lane = slice*8 + h; xor-shfl tree).
// Per chunk: 16 values/lane in registers, ns rounds of {local scan ->
// 64-lane butterfly -> in-register removal} (tie-break: value desc,
// index asc). Winners -> LDS; wave 0 merges 100 candidates (exact
// old-topk2 semantics). This is the R15 version (best measured: 324.7).
// ---------------------------------------------------------------------------
__global__ __launch_bounds__(640) void k_topk(
        const float* __restrict__ S, const float* __restrict__ Zpart,
        float* __restrict__ out, int c0, int ns) {
    int b = blockIdx.x, z = blockIdx.y;
    int c = c0 + z;
    int tid = threadIdx.x;
    int lane = tid & 63, w = tid >> 6;   // w in 0..9
    const float* Sc = S + (size_t)z * SSZ;

    __shared__ float2 wcand[NCH * 8];    // [chunk*ns + j], ns <= 8

    // ---- Z (all 64 lanes): h = lane&7, slice = lane>>3 over nc ----
    float zrl;
    {
        int h = lane & 7, sl = lane >> 3;
        const float* zp = Zpart + (size_t)c * 256 + b * 8 + h;
        float s = 0.f;
        for (int nc = sl; nc < NC3; nc += 8)
            s += zp[(size_t)nc * (C_ * 256)];
        s += __shfl_xor(s, 8, 64);
        s += __shfl_xor(s, 16, 64);
        s += __shfl_xor(s, 32, 64);
        zrl = 0.125f / s;
    }
    float zr[H_];
    #pragma unroll
    for (int h = 0; h < H_; ++h) zr[h] = __shfl(zrl, h, 64);

    // ---- per-wave: 2 chunks sequentially ----
    for (int p = 0; p < 2; ++p) {
        int chunk = w * 2 + p;
        int base = chunk * CHUNK + lane * 4;   // slot s=j*4+t -> n=base+j*256+t
        float va[16];
        #pragma unroll
        for (int s = 0; s < 16; ++s) va[s] = 0.f;
        bool ok[4];
        #pragma unroll
        for (int j = 0; j < 4; ++j) ok[j] = (base + j * 256) < N_;  // N_%4==0

        #pragma unroll
        for (int h = 0; h < H_; ++h) {
            const float* row = Sc + (size_t)(b * H_ + h) * N_;
            float wz = zr[h];
            #pragma unroll
            for (int j = 0; j < 4; ++j) {
                if (ok[j]) {
                    const float4 sv = *(const float4*)&row[base + j * 256];
                    va[j * 4 + 0] += sv.x * wz;
                    va[j * 4 + 1] += sv.y * wz;
                    va[j * 4 + 2] += sv.z * wz;
                    va[j * 4 + 3] += sv.w * wz;
                }
            }
        }
        #pragma unroll
        for (int j = 0; j < 4; ++j)
            if (!ok[j]) {
                va[j * 4 + 0] = -1.f; va[j * 4 + 1] = -1.f;
                va[j * 4 + 2] = -1.f; va[j * 4 + 3] = -1.f;
            }

        for (int j = 0; j < ns; ++j) {
            // local max over 16 slots; ascending scan + strict > = lowest n
            float bv = va[0]; int bs = 0;
            #pragma unroll
            for (int s = 1; s < 16; ++s)
                if (va[s] > bv) { bv = va[s]; bs = s; }
            int bn = ok[bs >> 2] ? (base + ((bs >> 2) << 8) + (bs & 3)) : N_;
            // 64-lane butterfly (all lanes converge on wave winner)
            #pragma unroll
            for (int off = 1; off < 64; off <<= 1) {
                float ov = __shfl_xor(bv, off, 64);
                int   on = __shfl_xor(bn, off, 64);
                if (ov > bv || (ov == bv && on < bn)) { bv = ov; bn = on; }
            }
            if (lane == 0) wcand[chunk * ns + j] = make_float2(bv, (float)bn);
            // in-register removal: only the owner lane matches bn
            #pragma unroll
            for (int s = 0; s < 16; ++s) {
                int n_s = base + ((s >> 2) << 8) + (s & 3);
                if (n_s == bn) va[s] = -2.f;
            }
        }
    }
    __syncthreads();

    // ---- wave 0: merge 100 candidates (exact old-topk2 semantics) ----
    if (w == 0) {
        int ncand = NCH * ns;   // 100
        float v0 = -3.f, v1 = -3.f;
        int   i0 = N_ + 1, i1 = N_ + 2;
        if (lane < ncand)      { float2 e = wcand[lane];      v0 = e.x; i0 = (int)e.y; }
        if (lane + 64 < ncand) { float2 e = wcand[lane + 64]; v1 = e.x; i1 = (int)e.y; }
        for (int j = 0; j < ns; ++j) {
            float bv = v0; int bn = i0;
            if (v1 > bv || (v1 == bv && i1 < bn)) { bv = v1; bn = i1; }
            #pragma unroll
            for (int off = 1; off < 64; off <<= 1) {
                float ov = __shfl_xor(bv, off, 64);
                int   on = __shfl_xor(bn, off, 64);
                if (ov > bv || (ov == bv && on < bn)) { bv = ov; bn = on; }
            }
            if (lane == 0) {
                out[((size_t)b * C_ + c) * ns + j] = (float)bn;
                out[(size_t)B_ * C_ * ns + ((size_t)b * C_ + c) * ns + j] = bv;
            }
            if (i0 == bn) v0 = -3.f;
            if (i1 == bn) v1 = -3.f;
        }
    }
}

// ---------------------------------------------------------------------------
extern "C" void kernel_launch(void* const* d_in, const int* in_sizes, int n_in,
                              void* d_out, int out_size, void* d_ws, size_t ws_size,
                              hipStream_t stream) {
    const float* x    = (const float*)d_in[0];  // (B,E)
    const float* A    = (const float*)d_in[1];  // (N,E)
    const int*   mask = (const int*)  d_in[2];  // (N,C)
    const float* Wq   = (const float*)d_in[3];  // (C,E,E)
    const float* bq   = (const float*)d_in[4];  // (C,E)
    const float* Wk   = (const float*)d_in[5];  // (C,E,E)
    const float* bk   = (const float*)d_in[6];  // (C,E)
    float* out = (float*)d_out;

    int ns = out_size / (2 * B_ * C_);          // = n_samples (5)

    // Workspace carve (floats)
    float* ws = (float*)d_ws;
    float* q     = ws;                                    // 131072
    float* qb    = q  + (size_t)C_ * B_ * E_;             // 2048
    float* Zpart = qb + (size_t)C_ * B_ * H_;             // NC3*8*256 = 321536
    short* u2    = (short*)(Zpart + (size_t)NC3 * C_ * 256);   // 2*1048576 shorts
    short* A2t   = u2 + 2 * U2P;                               // NC3*16*8192 shorts
    float* S     = (float*)(A2t + (size_t)NC3 * 16 * 8192);
    size_t fixedFloats = (size_t)(S - ws);

    int CB = 8;
    while (CB > 1 && (fixedFloats + (size_t)CB * SSZ + 16) * 4 > ws_size)
        CB >>= 1;

    k_prep<<<NC3 * 16 + 512, 256, 0, stream>>>(A, A2t, x, Wq, bq, q);
    k_u2<<<dim3(8, H_, C_), 256, 0, stream>>>(q, Wk, bk, u2, qb);

    for (int c0 = 0; c0 < C_; c0 += CB) {
        // grid: (g, z, mh, x) packed; 2 m-half blocks per (nc, c)
        k_scores_mfma<<<NCG * 2 * 8 * CB, 256, 0, stream>>>(u2, A2t, qb, mask, S, Zpart, c0, CB);
        k_topk<<<dim3(B_, CB), 640, 0, stream>>>(S, Zpart, out, c0, ns);
    }
}

// Round 13
// 318.475 us; speedup vs baseline: 1.2163x; 1.0022x over previous
//
#include <hip/hip_runtime.h>
#include <math.h>

// Problem constants (fixed by setup_inputs)
#define B_  32
#define N_  20000
#define C_  8
#define E_  512
#define H_  8
#define SCALE 0.125f    // 1/sqrt(64)
#define UNSC  9.765625e-4f   // 1/1024 = 1/(32*32) operand pre-scale undo

#define CHUNK 1024
#define NCH   20       // ceil(20000/1024) (top-k chunking)
#define NC3   157      // ceil(20000/128)  (GEMM n-chunks, BN=128)
#define NCG   20       // ceil(NC3/8) nc-groups for XCD swizzle
#define SSZ ((size_t)B_ * H_ * N_)   // per-class S floats (256*20000)

typedef __attribute__((ext_vector_type(8))) _Float16 h8_t;  // 8 fp16 (4 VGPRs)
typedef __attribute__((ext_vector_type(8))) short   s8_t;   // 8 shorts (16 B)
typedef __attribute__((ext_vector_type(4))) float f32x4;    // 16x16 MFMA acc / 16B ld

#define MFMAH(a, b, c) __builtin_amdgcn_mfma_f32_16x16x32_f16(a, b, c, 0, 0, 0)

// async global->LDS, 16B per lane, wave-uniform LDS base + lane*16
#define GLOAD_LDS16(g, l)                                              \
    __builtin_amdgcn_global_load_lds(                                  \
        (const __attribute__((address_space(1))) unsigned int*)(g),    \
        (__attribute__((address_space(3))) unsigned int*)(l), 16, 0, 0)

// RNE round-to-fp16, returns bit pattern + rounded value
__device__ inline unsigned short f16_round(float x, float& fv) {
    _Float16 h = (_Float16)x;
    fv = (float)h;
    union { _Float16 hh; unsigned short us; } u;
    u.hh = h;
    return u.us;
}

#define U2P ((size_t)C_ * 16 * 16 * 512)   // 1,048,576 shorts per plane

// ---------------------------------------------------------------------------
// K_prep: fused [k_split_A2 || k_q2] — independent works, one launch.
// blocks [0, NC3*16): A-split (nc = bid>>4, ks = bid&15), R5 swizzle layout.
// blocks [NC3*16, NC3*16+512): q2 (ft = r&63, c = r>>6).
// ---------------------------------------------------------------------------
__global__ __launch_bounds__(256) void k_prep(
        const float* __restrict__ A, short* __restrict__ A2t,
        const float* __restrict__ x, const float* __restrict__ Wq,
        const float* __restrict__ bq, float* __restrict__ q) {
    int bid = blockIdx.x;
    int tid = threadIdx.x;
    if (bid < NC3 * 16) {
        // ---- A-split: 2 fp16 planes, (nchunk 128, kstep 32) tiles ----
        int nc = bid >> 4, ks = bid & 15;
        int n = tid >> 1, kg = (tid & 1) * 2;   // logical chunks kg, kg+1 of 4
        int gn = nc * 128 + n;
        const float* ap = A + (size_t)gn * 512 + ks * 32 + kg * 8;
        s8_t vh[2], vm[2];
        #pragma unroll
        for (int g = 0; g < 2; ++g)
            #pragma unroll
            for (int j = 0; j < 8; ++j) {
                float xv = (gn < N_) ? ap[g * 8 + j] * 32.0f : 0.f;
                float fh, fm;
                vh[g][j] = (short)f16_round(xv, fh);
                vm[g][j] = (short)f16_round(xv - fh, fm);
            }
        short* outp = A2t + ((size_t)nc * 16 + ks) * 8192 + n * 32;
        #pragma unroll
        for (int g = 0; g < 2; ++g) {
            int p = ((kg + g) + (n >> 1)) & 3;
            *(s8_t*)(outp + p * 8)        = vh[g];
            *(s8_t*)(outp + 4096 + p * 8) = vm[g];
        }
    } else {
        // ---- q2: q(c,b,f) = sum_e x(b,e) * Wq[c][f,e] + bq[c][f] ----
        int r = bid - NC3 * 16;
        int ft = r & 63, c = r >> 6;
        int f0 = ft * 8;
        __shared__ float wsm[8][66];
        __shared__ float xs[32][66];
        int b = tid & 31, fs = tid >> 5;
        float acc = 0.f;
        const float* W = Wq + (size_t)c * E_ * E_;
        for (int k0 = 0; k0 < E_; k0 += 64) {
            __syncthreads();
            for (int i = tid; i < 512; i += 256)
                wsm[i >> 6][i & 63] = W[(size_t)(f0 + (i >> 6)) * E_ + k0 + (i & 63)];
            for (int i = tid; i < 2048; i += 256)
                xs[i >> 6][i & 63] = x[(size_t)(i >> 6) * E_ + k0 + (i & 63)];
            __syncthreads();
            #pragma unroll
            for (int kk = 0; kk < 64; ++kk)
                acc += xs[b][kk] * wsm[fs][kk];
        }
        q[((size_t)c * B_ + b) * E_ + f0 + fs] = acc + bq[c * E_ + f0 + fs];
    }
}

// ---------------------------------------------------------------------------
// K1b: u(c, m=(b*8+h), e) = sum_d q(c,b,h*64+d) * Wk[c][h*64+d, e], written
// DIRECTLY as 2 fp16 planes in 16x16x32 A-fragment order. 512 blocks.
// ---------------------------------------------------------------------------
__global__ __launch_bounds__(256) void k_u2(
        const float* __restrict__ q, const float* __restrict__ Wk,
        const float* __restrict__ bk, short* __restrict__ u2,
        float* __restrict__ qb) {
    int et = blockIdx.x, h = blockIdx.y, c = blockIdx.z;
    int e0 = et * 64;
    __shared__ float qs[32][66];
    __shared__ float wk[64][66];
    int tid = threadIdx.x;
    int b = tid & 31, es = tid >> 5;
    for (int i = tid; i < 2048; i += 256)
        qs[i >> 6][i & 63] = q[((size_t)c * B_ + (i >> 6)) * E_ + h * 64 + (i & 63)];
    const float* W = Wk + (size_t)c * E_ * E_ + (size_t)(h * 64) * E_;
    for (int i = tid; i < 4096; i += 256)
        wk[i >> 6][i & 63] = W[(size_t)(i >> 6) * E_ + e0 + (i & 63)];
    __syncthreads();
    float acc[8] = {};
    for (int d = 0; d < 64; ++d) {
        float qv = qs[b][d];
        #pragma unroll
        for (int j = 0; j < 8; ++j)
            acc[j] += qv * wk[d][es * 8 + j];
    }
    int m   = b * 8 + h;
    int e0s = e0 + es * 8;
    int ks  = e0s >> 5, quad = (e0s & 31) >> 3;
    int lane = (m & 15) + 16 * quad;
    int mt  = m >> 4;
    size_t base = ((((size_t)c * 16 + mt) * 16 + ks) * 512) + (size_t)lane * 8;
    s8_t vh, vm;
    #pragma unroll
    for (int j = 0; j < 8; ++j) {
        float xv = acc[j] * 32.0f, fh, fm;
        vh[j] = (short)f16_round(xv, fh);
        vm[j] = (short)f16_round(xv - fh, fm);
    }
    *(s8_t*)(u2 + base)       = vh;
    *(s8_t*)(u2 + U2P + base) = vm;
    if (et == 0 && es == 0) {
        float s = 0.f;
        const float* bkr = bk + c * E_ + h * 64;
        for (int d = 0; d < 64; ++d) s += qs[b][d] * bkr[d];
        qb[c * 256 + b * 8 + h] = s;
    }
}

// ---------------------------------------------------------------------------
// Main: S(m,n) = member ? exp(SCALE*(dot/1024 + qb)) : 0, 3-product fp16x2
// (hh, hm, mh) via 16x16x32 f16 MFMA.
// Verified local optimum: (256,4), 32x128 wave tile, f32 S.
// - occupancy ladder: 2w 147us / 3w 123 / 4w 118.6 / 6w(32x64) 128.5
// - schedule experiments (dbuf, 4-phase+setprio): both perfect nulls
// - fp16 S: index flips (R19); f32 S required
// R21: S stored with NONTEMPORAL stores — S has zero reuse in this kernel;
// streaming it past L2 protects the A2t/u2 L2 residency (measured FETCH
// 93-127 MB vs ~78 MB ideal = write-stream thrash). Bitwise-identical data.
// ---------------------------------------------------------------------------
__global__ __launch_bounds__(256, 4) void k_scores_mfma(
        const short* __restrict__ u2, const short* __restrict__ A2t,
        const float* __restrict__ qb, const int* __restrict__ mask,
        float* __restrict__ S, float* __restrict__ Zpart, int c0, int CB) {
    __shared__ __align__(16) short As[16384];   // one 32 KB ks2-tile (2 kh)
    __shared__ float sQb[128];
    __shared__ int   sMask[128];
    int bx = blockIdx.x;
    int x     = bx & 7;
    int rest  = bx >> 3;
    int mh    = rest & 1;          // m-half: rows [mh*128, mh*128+128)
    int rest2 = rest >> 1;
    int z     = rest2 % CB;
    int g     = rest2 / CB;
    int nc    = g * 8 + x;
    if (nc >= NC3) return;
    int c  = c0 + z;
    int tid = threadIdx.x;
    int lane = tid & 63, w = tid >> 6;
    int quad = lane >> 4, l15 = lane & 15;
    int n0 = nc * 128;

    if (tid < 128) {
        sQb[tid] = qb[c * 256 + mh * 128 + tid];
        int n = n0 + tid;
        sMask[tid] = (n < N_) ? mask[(size_t)n * C_ + c] : 0;
    }

    f32x4 acc[2][8];   // [mt][nt] — wave owns 32 rows x 128 cols
    #pragma unroll
    for (int i = 0; i < 2; ++i)
        #pragma unroll
        for (int j = 0; j < 8; ++j)
            acc[i][j] = (f32x4){0.f, 0.f, 0.f, 0.f};

    const char* tb = (const char*)A2t + (size_t)nc * 262144;

    for (int ks2 = 0; ks2 < 8; ++ks2) {
        __syncthreads();   // all waves done reading As (and covers sQb/sMask)
        // async DMA this ks2's 32 KB (two 16 KB kh tiles): 32 segs of 1024 B
        const char* src = tb + (size_t)ks2 * 32768;
        #pragma unroll
        for (int t = 0; t < 8; ++t) {
            int seg = w * 8 + t;
            GLOAD_LDS16(src + (size_t)seg * 1024 + lane * 16,
                        (char*)As + seg * 1024);
        }
        __syncthreads();   // compiler drains vmcnt(0) before barrier

        #pragma unroll
        for (int kh = 0; kh < 2; ++kh) {
            int ks = ks2 * 2 + kh;
            const short* Ab = As + kh * 8192;
            // A-fragments (u2): 4 global 16B loads, L2/LLC-resident
            h8_t af[2][2];
            #pragma unroll
            for (int mt = 0; mt < 2; ++mt) {
                int mtg = mh * 8 + w * 2 + mt;
                size_t ub = ((((size_t)c * 16 + mtg) * 16 + ks) * 512)
                            + (size_t)lane * 8;
                af[mt][0] = *(const h8_t*)(u2 + ub);
                af[mt][1] = *(const h8_t*)(u2 + U2P + ub);
            }
            // two nt-halves; sched_barrier caps b-frag hoisting (reg budget)
            #pragma unroll
            for (int half = 0; half < 2; ++half) {
                __builtin_amdgcn_sched_barrier(0);
                #pragma unroll
                for (int q4 = 0; q4 < 4; ++q4) {
                    int nt = half * 4 + q4;
                    int r = nt * 16 + l15;
                    const short* bp = Ab + r * 32 + ((quad + (r >> 1)) & 3) * 8;
                    h8_t b0 = *(const h8_t*)bp;
                    h8_t b1 = *(const h8_t*)(bp + 4096);
                    #pragma unroll
                    for (int mt = 0; mt < 2; ++mt) {
                        f32x4 a = acc[mt][nt];
                        a = MFMAH(af[mt][0], b0, a);   // hh
                        a = MFMAH(af[mt][0], b1, a);   // hm
                        a = MFMAH(af[mt][1], b0, a);   // mh
                        acc[mt][nt] = a;
                    }
                }
            }
        }
    }

    // Epilogue: unscale + bias + mask + exp, write S (nontemporal), fused
    // deterministic row-sums.  C/D: col = lane&15, row = quad*4 + r.
    float* Sc = S + (size_t)z * SSZ;
    #pragma unroll
    for (int mt = 0; mt < 2; ++mt) {
        float rs[4] = {0.f, 0.f, 0.f, 0.f};
        #pragma unroll
        for (int nt = 0; nt < 8; ++nt) {
            int nl = nt * 16 + l15;
            int n = n0 + nl;
            int mem = sMask[nl];
            #pragma unroll
            for (int r = 0; r < 4; ++r) {
                int ml = w * 32 + mt * 16 + quad * 4 + r;   // local row in half
                float sc = SCALE * (acc[mt][nt][r] * UNSC + sQb[ml]);
                float ev = mem ? __expf(sc) : 0.f;
                rs[r] += ev;
                if (n < N_)
                    __builtin_nontemporal_store(
                        ev, &Sc[(size_t)(mh * 128 + ml) * N_ + n]);
            }
        }
        #pragma unroll
        for (int r = 0; r < 4; ++r) {
            float v = rs[r];
            v += __shfl_xor(v, 1); v += __shfl_xor(v, 2);
            v += __shfl_xor(v, 4); v += __shfl_xor(v, 8);
            if (l15 == 0) {
                int ml = w * 32 + mt * 16 + quad * 4 + r;
                Zpart[((size_t)nc * C_ + c) * 256 + mh * 128 + ml] = v;
            }
        }
    }
}

// ---------------------------------------------------------------------------
// K3: fully fused [Z-sum + head-average + chunk top-ns + final merge].
// grid (B, CB), block 640 = 10 waves; wave w owns chunks {2w, 2w+1}.
// R21: S loads nontemporal (each element read exactly once chip-wide).
// Z: parallel across all 64 lanes (lane = slice*8 + h; xor-shfl tree).
// Per chunk: 16 values/lane in registers, ns rounds of {local scan ->
// 64-lane butterfly -> in-register removal} (tie-break: value desc,
// index asc). Winners -> LDS; wave 0 merges 100 candidates.
// ---------------------------------------------------------------------------
__global__ __launch_bounds__(640) void k_topk(
        const float* __restrict__ S, const float* __restrict__ Zpart,
        float* __restrict__ out, int c0, int ns) {
    int b = blockIdx.x, z = blockIdx.y;
    int c = c0 + z;
    int tid = threadIdx.x;
    int lane = tid & 63, w = tid >> 6;   // w in 0..9
    const float* Sc = S + (size_t)z * SSZ;

    __shared__ float2 wcand[NCH * 8];    // [chunk*ns + j], ns <= 8

    // ---- Z (all 64 lanes): h = lane&7, slice = lane>>3 over nc ----
    float zrl;
    {
        int h = lane & 7, sl = lane >> 3;
        const float* zp = Zpart + (size_t)c * 256 + b * 8 + h;
        float s = 0.f;
        for (int nc = sl; nc < NC3; nc += 8)
            s += zp[(size_t)nc * (C_ * 256)];
        s += __shfl_xor(s, 8, 64);
        s += __shfl_xor(s, 16, 64);
        s += __shfl_xor(s, 32, 64);
        zrl = 0.125f / s;
    }
    float zr[H_];
    #pragma unroll
    for (int h = 0; h < H_; ++h) zr[h] = __shfl(zrl, h, 64);

    // ---- per-wave: 2 chunks sequentially ----
    for (int p = 0; p < 2; ++p) {
        int chunk = w * 2 + p;
        int base = chunk * CHUNK + lane * 4;   // slot s=j*4+t -> n=base+j*256+t
        float va[16];
        #pragma unroll
        for (int s = 0; s < 16; ++s) va[s] = 0.f;
        bool ok[4];
        #pragma unroll
        for (int j = 0; j < 4; ++j) ok[j] = (base + j * 256) < N_;  // N_%4==0

        #pragma unroll
        for (int h = 0; h < H_; ++h) {
            const float* row = Sc + (size_t)(b * H_ + h) * N_;
            float wz = zr[h];
            #pragma unroll
            for (int j = 0; j < 4; ++j) {
                if (ok[j]) {
                    f32x4 sv = __builtin_nontemporal_load(
                        (const f32x4*)&row[base + j * 256]);
                    va[j * 4 + 0] += sv[0] * wz;
                    va[j * 4 + 1] += sv[1] * wz;
                    va[j * 4 + 2] += sv[2] * wz;
                    va[j * 4 + 3] += sv[3] * wz;
                }
            }
        }
        #pragma unroll
        for (int j = 0; j < 4; ++j)
            if (!ok[j]) {
                va[j * 4 + 0] = -1.f; va[j * 4 + 1] = -1.f;
                va[j * 4 + 2] = -1.f; va[j * 4 + 3] = -1.f;
            }

        for (int j = 0; j < ns; ++j) {
            // local max over 16 slots; ascending scan + strict > = lowest n
            float bv = va[0]; int bs = 0;
            #pragma unroll
            for (int s = 1; s < 16; ++s)
                if (va[s] > bv) { bv = va[s]; bs = s; }
            int bn = ok[bs >> 2] ? (base + ((bs >> 2) << 8) + (bs & 3)) : N_;
            // 64-lane butterfly (all lanes converge on wave winner)
            #pragma unroll
            for (int off = 1; off < 64; off <<= 1) {
                float ov = __shfl_xor(bv, off, 64);
                int   on = __shfl_xor(bn, off, 64);
                if (ov > bv || (ov == bv && on < bn)) { bv = ov; bn = on; }
            }
            if (lane == 0) wcand[chunk * ns + j] = make_float2(bv, (float)bn);
            // in-register removal: only the owner lane matches bn
            #pragma unroll
            for (int s = 0; s < 16; ++s) {
                int n_s = base + ((s >> 2) << 8) + (s & 3);
                if (n_s == bn) va[s] = -2.f;
            }
        }
    }
    __syncthreads();

    // ---- wave 0: merge 100 candidates (exact old-topk2 semantics) ----
    if (w == 0) {
        int ncand = NCH * ns;   // 100
        float v0 = -3.f, v1 = -3.f;
        int   i0 = N_ + 1, i1 = N_ + 2;
        if (lane < ncand)      { float2 e = wcand[lane];      v0 = e.x; i0 = (int)e.y; }
        if (lane + 64 < ncand) { float2 e = wcand[lane + 64]; v1 = e.x; i1 = (int)e.y; }
        for (int j = 0; j < ns; ++j) {
            float bv = v0; int bn = i0;
            if (v1 > bv || (v1 == bv && i1 < bn)) { bv = v1; bn = i1; }
            #pragma unroll
            for (int off = 1; off < 64; off <<= 1) {
                float ov = __shfl_xor(bv, off, 64);
                int   on = __shfl_xor(bn, off, 64);
                if (ov > bv || (ov == bv && on < bn)) { bv = ov; bn = on; }
            }
            if (lane == 0) {
                out[((size_t)b * C_ + c) * ns + j] = (float)bn;
                out[(size_t)B_ * C_ * ns + ((size_t)b * C_ + c) * ns + j] = bv;
            }
            if (i0 == bn) v0 = -3.f;
            if (i1 == bn) v1 = -3.f;
        }
    }
}

// ---------------------------------------------------------------------------
extern "C" void kernel_launch(void* const* d_in, const int* in_sizes, int n_in,
                              void* d_out, int out_size, void* d_ws, size_t ws_size,
                              hipStream_t stream) {
    const float* x    = (const float*)d_in[0];  // (B,E)
    const float* A    = (const float*)d_in[1];  // (N,E)
    const int*   mask = (const int*)  d_in[2];  // (N,C)
    const float* Wq   = (const float*)d_in[3];  // (C,E,E)
    const float* bq   = (const float*)d_in[4];  // (C,E)
    const float* Wk   = (const float*)d_in[5];  // (C,E,E)
    const float* bk   = (const float*)d_in[6];  // (C,E)
    float* out = (float*)d_out;

    int ns = out_size / (2 * B_ * C_);          // = n_samples (5)

    // Workspace carve (floats)
    float* ws = (float*)d_ws;
    float* q     = ws;                                    // 131072
    float* qb    = q  + (size_t)C_ * B_ * E_;             // 2048
    float* Zpart = qb + (size_t)C_ * B_ * H_;             // NC3*8*256 = 321536
    short* u2    = (short*)(Zpart + (size_t)NC3 * C_ * 256);   // 2*1048576 shorts
    short* A2t   = u2 + 2 * U2P;                               // NC3*16*8192 shorts
    float* S     = (float*)(A2t + (size_t)NC3 * 16 * 8192);
    size_t fixedFloats = (size_t)(S - ws);

    int CB = 8;
    while (CB > 1 && (fixedFloats + (size_t)CB * SSZ + 16) * 4 > ws_size)
        CB >>= 1;

    k_prep<<<NC3 * 16 + 512, 256, 0, stream>>>(A, A2t, x, Wq, bq, q);
    k_u2<<<dim3(8, H_, C_), 256, 0, stream>>>(q, Wk, bk, u2, qb);

    for (int c0 = 0; c0 < C_; c0 += CB) {
        // grid: (g, z, mh, x) packed; 2 m-half blocks per (nc, c)
        k_scores_mfma<<<NCG * 2 * 8 * CB, 256, 0, stream>>>(u2, A2t, qb, mask, S, Zpart, c0, CB);
        k_topk<<<dim3(B_, CB), 640, 0, stream>>>(S, Zpart, out, c0, ns);
    }
}